// Round 1
// baseline (489.593 us; speedup 1.0000x reference)
//
#include <hip/hip_runtime.h>
#include <stdint.h>

#define NN 100000
#define NE 1000000
#define HID 128

typedef __attribute__((ext_vector_type(4))) float f32x4;
typedef __attribute__((ext_vector_type(4))) unsigned u32x4;
typedef __attribute__((ext_vector_type(8))) short short8;
typedef __attribute__((ext_vector_type(8))) __bf16 bf16x8;

union V8 { short8 s; bf16x8 b; };

__device__ __forceinline__ unsigned short f2bf(float f) {
    unsigned u = __float_as_uint(f);
    unsigned r = u + 0x7fffu + ((u >> 16) & 1u);
    return (unsigned short)(r >> 16);
}
__device__ __forceinline__ float bf2f(unsigned short h) {
    return __uint_as_float(((unsigned)h) << 16);
}

// ---- cast n_feat f32 -> bf16, 8 elems/thread ----
__global__ void k_cast(const float* __restrict__ in, unsigned* __restrict__ outp) {
    int t = blockIdx.x * blockDim.x + threadIdx.x;
    if (t >= NN * HID / 8) return;
    const f32x4* pin = (const f32x4*)in;
    f32x4 a = pin[2 * t], b = pin[2 * t + 1];
    u32x4 o;
    o[0] = (unsigned)f2bf(a[0]) | ((unsigned)f2bf(a[1]) << 16);
    o[1] = (unsigned)f2bf(a[2]) | ((unsigned)f2bf(a[3]) << 16);
    o[2] = (unsigned)f2bf(b[0]) | ((unsigned)f2bf(b[1]) << 16);
    o[3] = (unsigned)f2bf(b[2]) | ((unsigned)f2bf(b[3]) << 16);
    ((u32x4*)outp)[t] = o;
}

// ---- W_I*(2/3), W_O*(2/3), W_S*(1/3) -> bf16 [3][128][128]; combined bias ----
__global__ void k_prepw(const float* __restrict__ WI, const float* __restrict__ WO,
                        const float* __restrict__ WS, const float* __restrict__ bI,
                        const float* __restrict__ bO, const float* __restrict__ bS,
                        unsigned short* __restrict__ Wbf, float* __restrict__ biasc) {
    int t = blockIdx.x * blockDim.x + threadIdx.x;
    if (t < 3 * HID * HID) {
        int p = t >> 14, i = t & 16383;
        const float* Wsrc = (p == 0) ? WI : ((p == 1) ? WO : WS);
        float scale = (p == 2) ? (1.0f / 3.0f) : (2.0f / 3.0f);
        Wbf[t] = f2bf(Wsrc[i] * scale);
    }
    if (t < HID) biasc[t] = (2.0f / 3.0f) * (bI[t] + bO[t]) + (1.0f / 3.0f) * bS[t];
}

// ---- per-edge degree histogram ----
__global__ void k_deg(const int* __restrict__ src, const int* __restrict__ dst,
                      int* __restrict__ deg_in, int* __restrict__ deg_out) {
    int e = blockIdx.x * blockDim.x + threadIdx.x;
    if (e >= NE) return;
    atomicAdd(&deg_in[dst[e]], 1);
    atomicAdd(&deg_out[src[e]], 1);
}

// ---- scan pass 1: per-1024-chunk inclusive scan + chunk totals ----
__global__ void k_scan1(const int* __restrict__ deg, int* __restrict__ incl,
                        int* __restrict__ csum, int n) {
    __shared__ int wtot[4];
    int b = blockIdx.x, t = threadIdx.x;
    int lane = t & 63, w = t >> 6;
    int base = b * 1024 + t * 4;
    int v0 = (base + 0 < n) ? deg[base + 0] : 0;
    int v1 = (base + 1 < n) ? deg[base + 1] : 0;
    int v2 = (base + 2 < n) ? deg[base + 2] : 0;
    int v3 = (base + 3 < n) ? deg[base + 3] : 0;
    v1 += v0; v2 += v1; v3 += v2;
    int tsum = v3;
    int x = tsum;
    #pragma unroll
    for (int off = 1; off < 64; off <<= 1) {
        int y = __shfl_up(x, off);
        if (lane >= off) x += y;
    }
    if (lane == 63) wtot[w] = x;
    __syncthreads();
    int wbase = 0;
    for (int j = 0; j < w; ++j) wbase += wtot[j];
    int texcl = wbase + x - tsum;
    if (base + 0 < n) incl[base + 0] = texcl + v0;
    if (base + 1 < n) incl[base + 1] = texcl + v1;
    if (base + 2 < n) incl[base + 2] = texcl + v2;
    if (base + 3 < n) incl[base + 3] = texcl + v3;
    if (t == 255) csum[b] = wbase + x;
}

// ---- scan pass 2: add chunk offsets; emit row_ptr (excl) and cursor copy ----
__global__ void k_scan2(const int* __restrict__ incl, const int* __restrict__ csum,
                        const int* __restrict__ deg, int* __restrict__ row_ptr,
                        int* __restrict__ cursor, int n) {
    __shared__ int sh[4];
    int b = blockIdx.x, t = threadIdx.x;
    int lane = t & 63, w = t >> 6;
    int v = (t < b) ? csum[t] : 0;   // nchunks <= 256
    #pragma unroll
    for (int o = 32; o > 0; o >>= 1) v += __shfl_down(v, o);
    if (lane == 0) sh[w] = v;
    __syncthreads();
    int off = sh[0] + sh[1] + sh[2] + sh[3];
    int base = b * 1024 + t * 4;
    #pragma unroll
    for (int q = 0; q < 4; ++q) {
        int i = base + q;
        if (i < n) {
            int inc = off + incl[i];
            row_ptr[i + 1] = inc;
            cursor[i] = inc - deg[i];
        }
    }
    if (b == 0 && t == 0) row_ptr[0] = 0;
}

// ---- CSR fill (counting-sort scatter of neighbor ids) ----
__global__ void k_fill(const int* __restrict__ src, const int* __restrict__ dst,
                       int* __restrict__ cur_in, int* __restrict__ cur_out,
                       int* __restrict__ col_in, int* __restrict__ col_out) {
    int e = blockIdx.x * blockDim.x + threadIdx.x;
    if (e >= NE) return;
    int s = src[e], d = dst[e];
    int p1 = atomicAdd(&cur_in[d], 1);
    col_in[p1] = s;
    int p2 = atomicAdd(&cur_out[s], 1);
    col_out[p2] = d;
}

// ---- gather: one wave per node, both directions; writes comp as bf16 ----
__global__ void k_gather(const unsigned short* __restrict__ nf,
                         const float* __restrict__ e_fwd, const float* __restrict__ e_rev,
                         const int* __restrict__ row_in, const int* __restrict__ col_in,
                         const int* __restrict__ row_out, const int* __restrict__ col_out,
                         unsigned* __restrict__ comp_f, unsigned* __restrict__ comp_r) {
    int wid = (int)((blockIdx.x * blockDim.x + threadIdx.x) >> 6);
    int lane = threadIdx.x & 63;
    if (wid >= NN) return;
    #pragma unroll
    for (int dir = 0; dir < 2; ++dir) {
        const int* row = dir ? row_out : row_in;
        const int* col = dir ? col_out : col_in;
        const float* ev = dir ? e_rev : e_fwd;
        unsigned* outp = dir ? comp_r : comp_f;
        int rs = row[wid], re = row[wid + 1];
        int deg = re - rs;
        float a0 = 0.0f, a1 = 0.0f;
        int k = rs;
        while (k < re) {
            int cnt = re - k;
            if (cnt > 64) cnt = 64;
            int idx = 0;
            if (lane < cnt) idx = col[k + lane];
            for (int j = 0; j < cnt; ++j) {
                int s = __shfl(idx, j);
                unsigned pv = *(const unsigned*)(nf + (((size_t)s) << 7) + (lane << 1));
                a0 += bf2f((unsigned short)(pv & 0xffffu));
                a1 += bf2f((unsigned short)(pv >> 16));
            }
            k += cnt;
        }
        float degf = (float)deg;
        float rn = (deg > 0) ? (1.0f / sqrtf(degf)) : 1.0f;
        float c0 = (a0 - degf * ev[lane * 2 + 0]) * rn;
        float c1 = (a1 - degf * ev[lane * 2 + 1]) * rn;
        outp[(size_t)wid * 64 + lane] = (unsigned)f2bf(c0) | ((unsigned)f2bf(c1) << 16);
    }
}

// ---- fused 3-path GEMM: out = comp_f@WI'^T + comp_r@WO'^T + nf@WS'^T + biasc ----
__global__ __launch_bounds__(256) void k_gemm(
        const unsigned short* __restrict__ comp_f, const unsigned short* __restrict__ comp_r,
        const unsigned short* __restrict__ nf, const unsigned short* __restrict__ Wbf,
        const float* __restrict__ biasc, float* __restrict__ outp) {
    int w = threadIdx.x >> 6, lane = threadIdx.x & 63;
    int rowbase = blockIdx.x * 128 + w * 32;
    if (rowbase >= NN) return;
    int lm = lane & 15;
    int lk = (lane >> 4) * 8;

    f32x4 acc[2][8];
    #pragma unroll
    for (int m = 0; m < 2; ++m)
        #pragma unroll
        for (int n = 0; n < 8; ++n) {
            acc[m][n][0] = 0.0f; acc[m][n][1] = 0.0f;
            acc[m][n][2] = 0.0f; acc[m][n][3] = 0.0f;
        }

    #pragma unroll
    for (int p = 0; p < 3; ++p) {
        const unsigned short* A = (p == 0) ? comp_f : ((p == 1) ? comp_r : nf);
        const unsigned short* Wp = Wbf + p * HID * HID;
        #pragma unroll
        for (int kb = 0; kb < 4; ++kb) {
            int k0 = kb * 32 + lk;
            int r0 = rowbase + lm, r1 = r0 + 16;
            V8 a0, a1;
            a0.s = (short8){0,0,0,0,0,0,0,0};
            a1.s = a0.s;
            if (r0 < NN) a0.s = *(const short8*)(A + (size_t)r0 * HID + k0);
            if (r1 < NN) a1.s = *(const short8*)(A + (size_t)r1 * HID + k0);
            #pragma unroll
            for (int n = 0; n < 8; ++n) {
                V8 bb;
                bb.s = *(const short8*)(Wp + (size_t)(n * 16 + lm) * HID + k0);
                acc[0][n] = __builtin_amdgcn_mfma_f32_16x16x32_bf16(a0.b, bb.b, acc[0][n], 0, 0, 0);
                acc[1][n] = __builtin_amdgcn_mfma_f32_16x16x32_bf16(a1.b, bb.b, acc[1][n], 0, 0, 0);
            }
        }
    }
    // epilogue: D layout col=lane&15, row=(lane>>4)*4+i
    #pragma unroll
    for (int n = 0; n < 8; ++n) {
        int c = n * 16 + lm;
        float bias = biasc[c];
        #pragma unroll
        for (int m = 0; m < 2; ++m) {
            #pragma unroll
            for (int i = 0; i < 4; ++i) {
                int row = rowbase + m * 16 + (lane >> 4) * 4 + i;
                if (row < NN) outp[(size_t)row * HID + c] = acc[m][n][i] + bias;
            }
        }
    }
}

// ---- edge-feature update: e_out = W_rel @ e + b_rel (exact f32) ----
__global__ void k_evec(const float* __restrict__ W_rel, const float* __restrict__ b_rel,
                       const float* __restrict__ e_fwd, const float* __restrict__ e_rev,
                       float* __restrict__ outp) {
    int t = threadIdx.x;  // 256 threads: 0..127 fwd, 128..255 rev
    int c = t & 127;
    const float* e = (t < 128) ? e_fwd : e_rev;
    float s = b_rel[c];
    #pragma unroll 4
    for (int k = 0; k < HID; ++k) s += W_rel[c * HID + k] * e[k];
    outp[(size_t)NN * HID + ((t < 128) ? 0 : HID) + c] = s;
}

extern "C" void kernel_launch(void* const* d_in, const int* in_sizes, int n_in,
                              void* d_out, int out_size, void* d_ws, size_t ws_size,
                              hipStream_t stream) {
    const float* n_feat = (const float*)d_in[0];
    const float* e_fwd  = (const float*)d_in[1];
    const float* e_rev  = (const float*)d_in[2];
    const float* W_I    = (const float*)d_in[3];
    const float* b_I    = (const float*)d_in[4];
    const float* W_O    = (const float*)d_in[5];
    const float* b_O    = (const float*)d_in[6];
    const float* W_S    = (const float*)d_in[7];
    const float* b_S    = (const float*)d_in[8];
    const float* W_rel  = (const float*)d_in[9];
    const float* b_rel  = (const float*)d_in[10];
    const int*   src    = (const int*)d_in[11];
    const int*   dst    = (const int*)d_in[12];
    float* outp = (float*)d_out;

    uint8_t* ws = (uint8_t*)d_ws;
    size_t off = 0;
    auto alloc = [&](size_t bytes) -> size_t {
        size_t r = off;
        off = (off + bytes + 255) & ~(size_t)255;
        return r;
    };
    size_t o_nfbf   = alloc((size_t)NN * HID * 2);
    size_t o_compf  = alloc((size_t)NN * HID * 2);
    size_t o_compr  = alloc((size_t)NN * HID * 2);
    size_t o_wbf    = alloc((size_t)3 * HID * HID * 2);
    size_t o_biasc  = alloc(HID * 4);
    size_t o_degin  = alloc((size_t)NN * 4);
    size_t o_degout = alloc((size_t)NN * 4);
    size_t o_rowin  = alloc((size_t)(NN + 1) * 4);
    size_t o_rowout = alloc((size_t)(NN + 1) * 4);
    size_t o_curin  = alloc((size_t)NN * 4);
    size_t o_curout = alloc((size_t)NN * 4);
    size_t o_colin  = alloc((size_t)NE * 4);
    size_t o_colout = alloc((size_t)NE * 4);
    size_t o_tmp    = alloc((size_t)NN * 4);
    size_t o_csum   = alloc(256 * 4);
    (void)ws_size; (void)in_sizes; (void)n_in; (void)out_size; (void)o_csum;

    unsigned short* nfbf  = (unsigned short*)(ws + o_nfbf);
    unsigned*  compf_u    = (unsigned*)(ws + o_compf);
    unsigned*  compr_u    = (unsigned*)(ws + o_compr);
    unsigned short* wbf   = (unsigned short*)(ws + o_wbf);
    float*     biasc      = (float*)(ws + o_biasc);
    int* deg_in  = (int*)(ws + o_degin);
    int* deg_out = (int*)(ws + o_degout);
    int* row_in  = (int*)(ws + o_rowin);
    int* row_out = (int*)(ws + o_rowout);
    int* cur_in  = (int*)(ws + o_curin);
    int* cur_out = (int*)(ws + o_curout);
    int* col_in  = (int*)(ws + o_colin);
    int* col_out = (int*)(ws + o_colout);
    int* tmp     = (int*)(ws + o_tmp);
    int* csum    = (int*)(ws + o_csum);

    // zero both degree arrays (contiguous range incl. padding)
    hipMemsetAsync(ws + o_degin, 0, (o_degout - o_degin) + (size_t)NN * 4, stream);

    const int nchunks = (NN + 1023) / 1024;  // 98

    k_cast<<<(NN * HID / 8 + 255) / 256, 256, 0, stream>>>(n_feat, (unsigned*)nfbf);
    k_prepw<<<(3 * HID * HID + 255) / 256, 256, 0, stream>>>(W_I, W_O, W_S, b_I, b_O, b_S, wbf, biasc);
    k_deg<<<(NE + 255) / 256, 256, 0, stream>>>(src, dst, deg_in, deg_out);

    k_scan1<<<nchunks, 256, 0, stream>>>(deg_in, tmp, csum, NN);
    k_scan2<<<nchunks, 256, 0, stream>>>(tmp, csum, deg_in, row_in, cur_in, NN);
    k_scan1<<<nchunks, 256, 0, stream>>>(deg_out, tmp, csum, NN);
    k_scan2<<<nchunks, 256, 0, stream>>>(tmp, csum, deg_out, row_out, cur_out, NN);

    k_fill<<<(NE + 255) / 256, 256, 0, stream>>>(src, dst, cur_in, cur_out, col_in, col_out);

    k_gather<<<(NN + 3) / 4, 256, 0, stream>>>(nfbf, e_fwd, e_rev, row_in, col_in,
                                               row_out, col_out, compf_u, compr_u);

    k_gemm<<<(NN + 127) / 128, 256, 0, stream>>>((const unsigned short*)compf_u,
                                                 (const unsigned short*)compr_u,
                                                 nfbf, wbf, biasc, outp);

    k_evec<<<1, 256, 0, stream>>>(W_rel, b_rel, e_fwd, e_rev, outp);
}

// Round 2
// 299.165 us; speedup vs baseline: 1.6365x; 1.6365x over previous
//
#include <hip/hip_runtime.h>
#include <stdint.h>

#define NN 100000
#define NE 1000000
#define HID 128
#define NB 391            // ceil(NN/256) buckets of 256 nodes

typedef __attribute__((ext_vector_type(4))) float f32x4;
typedef __attribute__((ext_vector_type(4))) unsigned u32x4;
typedef __attribute__((ext_vector_type(8))) short short8;
typedef __attribute__((ext_vector_type(8))) __bf16 bf16x8;

union V8 { short8 s; bf16x8 b; };

__device__ __forceinline__ unsigned short f2bf(float f) {
    unsigned u = __float_as_uint(f);
    unsigned r = u + 0x7fffu + ((u >> 16) & 1u);
    return (unsigned short)(r >> 16);
}
__device__ __forceinline__ float bf2f(unsigned short h) {
    return __uint_as_float(((unsigned)h) << 16);
}

// ---- cast n_feat f32 -> bf16, 8 elems/thread ----
__global__ void k_cast(const float* __restrict__ in, unsigned* __restrict__ outp) {
    int t = blockIdx.x * blockDim.x + threadIdx.x;
    if (t >= NN * HID / 8) return;
    const f32x4* pin = (const f32x4*)in;
    f32x4 a = pin[2 * t], b = pin[2 * t + 1];
    u32x4 o;
    o[0] = (unsigned)f2bf(a[0]) | ((unsigned)f2bf(a[1]) << 16);
    o[1] = (unsigned)f2bf(a[2]) | ((unsigned)f2bf(a[3]) << 16);
    o[2] = (unsigned)f2bf(b[0]) | ((unsigned)f2bf(b[1]) << 16);
    o[3] = (unsigned)f2bf(b[2]) | ((unsigned)f2bf(b[3]) << 16);
    ((u32x4*)outp)[t] = o;
}

// ---- W_I*(2/3), W_O*(2/3), W_S*(1/3) -> bf16 [3][128][128]; combined bias ----
__global__ void k_prepw(const float* __restrict__ WI, const float* __restrict__ WO,
                        const float* __restrict__ WS, const float* __restrict__ bI,
                        const float* __restrict__ bO, const float* __restrict__ bS,
                        unsigned short* __restrict__ Wbf, float* __restrict__ biasc) {
    int t = blockIdx.x * blockDim.x + threadIdx.x;
    if (t < 3 * HID * HID) {
        int p = t >> 14, i = t & 16383;
        const float* Wsrc = (p == 0) ? WI : ((p == 1) ? WO : WS);
        float scale = (p == 2) ? (1.0f / 3.0f) : (2.0f / 3.0f);
        Wbf[t] = f2bf(Wsrc[i] * scale);
    }
    if (t < HID) biasc[t] = (2.0f / 3.0f) * (bI[t] + bO[t]) + (1.0f / 3.0f) * bS[t];
}

// ---- bucket counting: LDS histograms, one global atomic per (block,bucket) ----
__global__ __launch_bounds__(256) void k_bincount(
        const int* __restrict__ src, const int* __restrict__ dst,
        int* __restrict__ bcntD, int* __restrict__ bcntS) {
    __shared__ int hD[NB], hS[NB];
    int tid = threadIdx.x;
    for (int b = tid; b < NB; b += 256) { hD[b] = 0; hS[b] = 0; }
    __syncthreads();
    int base = blockIdx.x * 8192;
    #pragma unroll
    for (int i = 0; i < 32; ++i) {
        int e = base + i * 256 + tid;
        if (e < NE) {
            atomicAdd(&hD[dst[e] >> 8], 1);
            atomicAdd(&hS[src[e] >> 8], 1);
        }
    }
    __syncthreads();
    for (int b = tid; b < NB; b += 256) {
        if (hD[b]) atomicAdd(&bcntD[b], hD[b]);
        if (hS[b]) atomicAdd(&bcntS[b], hS[b]);
    }
}

// ---- scan bucket counts -> bases + cursors (one block, both dirs) ----
__global__ __launch_bounds__(512) void k_bucketscan(
        const int* __restrict__ bcntD, const int* __restrict__ bcntS,
        int* __restrict__ bbaseD, int* __restrict__ bbaseS,
        int* __restrict__ bcurD, int* __restrict__ bcurS) {
    __shared__ int wtot[8];
    int t = threadIdx.x, lane = t & 63, w = t >> 6;
    #pragma unroll
    for (int dir = 0; dir < 2; ++dir) {
        const int* cnt = dir ? bcntS : bcntD;
        int* bb = dir ? bbaseS : bbaseD;
        int* bc = dir ? bcurS : bcurD;
        int v = (t < NB) ? cnt[t] : 0;
        int x = v;
        #pragma unroll
        for (int off = 1; off < 64; off <<= 1) {
            int y = __shfl_up(x, off);
            if (lane >= off) x += y;
        }
        if (lane == 63) wtot[w] = x;
        __syncthreads();
        int wbase = 0;
        for (int j = 0; j < w; ++j) wbase += wtot[j];
        int incl = wbase + x;
        if (t < NB) { bb[t] = incl - v; bc[t] = incl - v; }
        if (t == NB - 1) bb[NB] = incl;
        __syncthreads();
    }
}

// ---- bin fill: scatter edges into bucket-contiguous packed arrays ----
// packed = (other_node << 8) | (key_node & 255)
__global__ __launch_bounds__(256) void k_binfill(
        const int* __restrict__ src, const int* __restrict__ dst,
        int* __restrict__ bcurD, int* __restrict__ bcurS,
        unsigned* __restrict__ binD, unsigned* __restrict__ binS) {
    __shared__ int hD[NB], hS[NB];
    int tid = threadIdx.x;
    for (int b = tid; b < NB; b += 256) { hD[b] = 0; hS[b] = 0; }
    __syncthreads();
    int base = blockIdx.x * 8192;
    int s[32], d[32];
    #pragma unroll
    for (int i = 0; i < 32; ++i) {
        int e = base + i * 256 + tid;
        s[i] = -1; d[i] = -1;
        if (e < NE) { s[i] = src[e]; d[i] = dst[e]; }
    }
    #pragma unroll
    for (int i = 0; i < 32; ++i) {
        if (s[i] >= 0) {
            atomicAdd(&hD[d[i] >> 8], 1);
            atomicAdd(&hS[s[i] >> 8], 1);
        }
    }
    __syncthreads();
    // reserve global ranges, turn LDS counters into cursors
    for (int b = tid; b < NB; b += 256) {
        int c = hD[b];
        hD[b] = c ? atomicAdd(&bcurD[b], c) : 0;
        c = hS[b];
        hS[b] = c ? atomicAdd(&bcurS[b], c) : 0;
    }
    __syncthreads();
    #pragma unroll
    for (int i = 0; i < 32; ++i) {
        if (s[i] >= 0) {
            int p = atomicAdd(&hD[d[i] >> 8], 1);
            binD[p] = ((unsigned)s[i] << 8) | ((unsigned)d[i] & 255u);
            int q = atomicAdd(&hS[s[i] >> 8], 1);
            binS[q] = ((unsigned)d[i] << 8) | ((unsigned)s[i] & 255u);
        }
    }
}

// ---- per-bucket counting sort -> CSR col + row_ptr (one block per bucket+dir) ----
__global__ __launch_bounds__(256) void k_bucketsort(
        const unsigned* __restrict__ binD, const unsigned* __restrict__ binS,
        const int* __restrict__ bbaseD, const int* __restrict__ bbaseS,
        int* __restrict__ row_in, int* __restrict__ row_out,
        int* __restrict__ col_in, int* __restrict__ col_out) {
    __shared__ int c[256];
    __shared__ int wtot[4];
    int bid = blockIdx.x;
    int dir = (bid >= NB) ? 1 : 0;
    int b = dir ? (bid - NB) : bid;
    const unsigned* bin = dir ? binS : binD;
    const int* bb = dir ? bbaseS : bbaseD;
    int* row = dir ? row_out : row_in;
    int* col = dir ? col_out : col_in;

    int tid = threadIdx.x, lane = tid & 63, w = tid >> 6;
    int base = bb[b], cnt = bb[b + 1] - base;
    int node0 = b << 8;
    int M = NN - node0; if (M > 256) M = 256;

    c[tid] = 0;
    __syncthreads();
    for (int k = tid; k < cnt; k += 256)
        atomicAdd(&c[bin[base + k] & 255u], 1);
    __syncthreads();
    int v = c[tid];
    int x = v;
    #pragma unroll
    for (int off = 1; off < 64; off <<= 1) {
        int y = __shfl_up(x, off);
        if (lane >= off) x += y;
    }
    if (lane == 63) wtot[w] = x;
    __syncthreads();
    int wbase = 0;
    for (int j = 0; j < w; ++j) wbase += wtot[j];
    int incl = wbase + x;
    if (tid < M) row[node0 + tid + 1] = base + incl;
    if (b == 0 && tid == 0) row[0] = 0;
    __syncthreads();
    c[tid] = base + incl - v;   // cursor = exclusive
    __syncthreads();
    for (int k = tid; k < cnt; k += 256) {
        unsigned pk = bin[base + k];
        int p = atomicAdd(&c[pk & 255u], 1);
        col[p] = (int)(pk >> 8);
    }
}

// ---- gather: one wave per node, both directions; writes comp as bf16 ----
__global__ void k_gather(const unsigned short* __restrict__ nf,
                         const float* __restrict__ e_fwd, const float* __restrict__ e_rev,
                         const int* __restrict__ row_in, const int* __restrict__ col_in,
                         const int* __restrict__ row_out, const int* __restrict__ col_out,
                         unsigned* __restrict__ comp_f, unsigned* __restrict__ comp_r) {
    int wid = (int)((blockIdx.x * blockDim.x + threadIdx.x) >> 6);
    int lane = threadIdx.x & 63;
    if (wid >= NN) return;
    #pragma unroll
    for (int dir = 0; dir < 2; ++dir) {
        const int* row = dir ? row_out : row_in;
        const int* col = dir ? col_out : col_in;
        const float* ev = dir ? e_rev : e_fwd;
        unsigned* outp = dir ? comp_r : comp_f;
        int rs = row[wid], re = row[wid + 1];
        int deg = re - rs;
        float a0 = 0.0f, a1 = 0.0f;
        int k = rs;
        while (k < re) {
            int cnt = re - k;
            if (cnt > 64) cnt = 64;
            int idx = 0;
            if (lane < cnt) idx = col[k + lane];
            for (int j = 0; j < cnt; ++j) {
                int s = __shfl(idx, j);
                unsigned pv = *(const unsigned*)(nf + (((size_t)s) << 7) + (lane << 1));
                a0 += bf2f((unsigned short)(pv & 0xffffu));
                a1 += bf2f((unsigned short)(pv >> 16));
            }
            k += cnt;
        }
        float degf = (float)deg;
        float rn = (deg > 0) ? (1.0f / sqrtf(degf)) : 1.0f;
        float c0 = (a0 - degf * ev[lane * 2 + 0]) * rn;
        float c1 = (a1 - degf * ev[lane * 2 + 1]) * rn;
        outp[(size_t)wid * 64 + lane] = (unsigned)f2bf(c0) | ((unsigned)f2bf(c1) << 16);
    }
}

// ---- fused 3-path GEMM: out = comp_f@WI'^T + comp_r@WO'^T + nf@WS'^T + biasc ----
__global__ __launch_bounds__(256) void k_gemm(
        const unsigned short* __restrict__ comp_f, const unsigned short* __restrict__ comp_r,
        const unsigned short* __restrict__ nf, const unsigned short* __restrict__ Wbf,
        const float* __restrict__ biasc, float* __restrict__ outp) {
    int w = threadIdx.x >> 6, lane = threadIdx.x & 63;
    int rowbase = blockIdx.x * 128 + w * 32;
    if (rowbase >= NN) return;
    int lm = lane & 15;
    int lk = (lane >> 4) * 8;

    f32x4 acc[2][8];
    #pragma unroll
    for (int m = 0; m < 2; ++m)
        #pragma unroll
        for (int n = 0; n < 8; ++n) {
            acc[m][n][0] = 0.0f; acc[m][n][1] = 0.0f;
            acc[m][n][2] = 0.0f; acc[m][n][3] = 0.0f;
        }

    #pragma unroll
    for (int p = 0; p < 3; ++p) {
        const unsigned short* A = (p == 0) ? comp_f : ((p == 1) ? comp_r : nf);
        const unsigned short* Wp = Wbf + p * HID * HID;
        #pragma unroll
        for (int kb = 0; kb < 4; ++kb) {
            int k0 = kb * 32 + lk;
            int r0 = rowbase + lm, r1 = r0 + 16;
            V8 a0, a1;
            a0.s = (short8){0,0,0,0,0,0,0,0};
            a1.s = a0.s;
            if (r0 < NN) a0.s = *(const short8*)(A + (size_t)r0 * HID + k0);
            if (r1 < NN) a1.s = *(const short8*)(A + (size_t)r1 * HID + k0);
            #pragma unroll
            for (int n = 0; n < 8; ++n) {
                V8 bb;
                bb.s = *(const short8*)(Wp + (size_t)(n * 16 + lm) * HID + k0);
                acc[0][n] = __builtin_amdgcn_mfma_f32_16x16x32_bf16(a0.b, bb.b, acc[0][n], 0, 0, 0);
                acc[1][n] = __builtin_amdgcn_mfma_f32_16x16x32_bf16(a1.b, bb.b, acc[1][n], 0, 0, 0);
            }
        }
    }
    #pragma unroll
    for (int n = 0; n < 8; ++n) {
        int cc = n * 16 + lm;
        float bias = biasc[cc];
        #pragma unroll
        for (int m = 0; m < 2; ++m) {
            #pragma unroll
            for (int i = 0; i < 4; ++i) {
                int row = rowbase + m * 16 + (lane >> 4) * 4 + i;
                if (row < NN) outp[(size_t)row * HID + cc] = acc[m][n][i] + bias;
            }
        }
    }
}

// ---- edge-feature update: e_out = W_rel @ e + b_rel (exact f32) ----
__global__ void k_evec(const float* __restrict__ W_rel, const float* __restrict__ b_rel,
                       const float* __restrict__ e_fwd, const float* __restrict__ e_rev,
                       float* __restrict__ outp) {
    int t = threadIdx.x;  // 256 threads: 0..127 fwd, 128..255 rev
    int cc = t & 127;
    const float* e = (t < 128) ? e_fwd : e_rev;
    float s = b_rel[cc];
    #pragma unroll 4
    for (int k = 0; k < HID; ++k) s += W_rel[cc * HID + k] * e[k];
    outp[(size_t)NN * HID + ((t < 128) ? 0 : HID) + cc] = s;
}

extern "C" void kernel_launch(void* const* d_in, const int* in_sizes, int n_in,
                              void* d_out, int out_size, void* d_ws, size_t ws_size,
                              hipStream_t stream) {
    const float* n_feat = (const float*)d_in[0];
    const float* e_fwd  = (const float*)d_in[1];
    const float* e_rev  = (const float*)d_in[2];
    const float* W_I    = (const float*)d_in[3];
    const float* b_I    = (const float*)d_in[4];
    const float* W_O    = (const float*)d_in[5];
    const float* b_O    = (const float*)d_in[6];
    const float* W_S    = (const float*)d_in[7];
    const float* b_S    = (const float*)d_in[8];
    const float* W_rel  = (const float*)d_in[9];
    const float* b_rel  = (const float*)d_in[10];
    const int*   src    = (const int*)d_in[11];
    const int*   dst    = (const int*)d_in[12];
    float* outp = (float*)d_out;

    uint8_t* ws = (uint8_t*)d_ws;
    size_t off = 0;
    auto alloc = [&](size_t bytes) -> size_t {
        size_t r = off;
        off = (off + bytes + 255) & ~(size_t)255;
        return r;
    };
    size_t o_nfbf   = alloc((size_t)NN * HID * 2);
    size_t o_compf  = alloc((size_t)NN * HID * 2);
    size_t o_compr  = alloc((size_t)NN * HID * 2);
    size_t o_wbf    = alloc((size_t)3 * HID * HID * 2);
    size_t o_biasc  = alloc(HID * 4);
    size_t o_rowin  = alloc((size_t)(NN + 1) * 4);
    size_t o_rowout = alloc((size_t)(NN + 1) * 4);
    size_t o_colin  = alloc((size_t)NE * 4);
    size_t o_colout = alloc((size_t)NE * 4);
    size_t o_binD   = alloc((size_t)NE * 4);
    size_t o_binS   = alloc((size_t)NE * 4);
    size_t o_bcnt   = alloc((size_t)2 * NB * 4);       // D then S, contiguous for memset
    size_t o_bbaseD = alloc((size_t)(NB + 1) * 4);
    size_t o_bbaseS = alloc((size_t)(NB + 1) * 4);
    size_t o_bcurD  = alloc((size_t)NB * 4);
    size_t o_bcurS  = alloc((size_t)NB * 4);
    (void)ws_size; (void)in_sizes; (void)n_in; (void)out_size;

    unsigned short* nfbf  = (unsigned short*)(ws + o_nfbf);
    unsigned*  compf_u    = (unsigned*)(ws + o_compf);
    unsigned*  compr_u    = (unsigned*)(ws + o_compr);
    unsigned short* wbf   = (unsigned short*)(ws + o_wbf);
    float*     biasc      = (float*)(ws + o_biasc);
    int* row_in  = (int*)(ws + o_rowin);
    int* row_out = (int*)(ws + o_rowout);
    int* col_in  = (int*)(ws + o_colin);
    int* col_out = (int*)(ws + o_colout);
    unsigned* binD = (unsigned*)(ws + o_binD);
    unsigned* binS = (unsigned*)(ws + o_binS);
    int* bcntD   = (int*)(ws + o_bcnt);
    int* bcntS   = bcntD + NB;
    int* bbaseD  = (int*)(ws + o_bbaseD);
    int* bbaseS  = (int*)(ws + o_bbaseS);
    int* bcurD   = (int*)(ws + o_bcurD);
    int* bcurS   = (int*)(ws + o_bcurS);

    hipMemsetAsync(ws + o_bcnt, 0, (size_t)2 * NB * 4, stream);

    k_cast<<<(NN * HID / 8 + 255) / 256, 256, 0, stream>>>(n_feat, (unsigned*)nfbf);
    k_prepw<<<(3 * HID * HID + 255) / 256, 256, 0, stream>>>(W_I, W_O, W_S, b_I, b_O, b_S, wbf, biasc);

    const int nbinblk = (NE + 8191) / 8192;  // 123
    k_bincount<<<nbinblk, 256, 0, stream>>>(src, dst, bcntD, bcntS);
    k_bucketscan<<<1, 512, 0, stream>>>(bcntD, bcntS, bbaseD, bbaseS, bcurD, bcurS);
    k_binfill<<<nbinblk, 256, 0, stream>>>(src, dst, bcurD, bcurS, binD, binS);
    k_bucketsort<<<2 * NB, 256, 0, stream>>>(binD, binS, bbaseD, bbaseS,
                                             row_in, row_out, col_in, col_out);

    k_gather<<<(NN + 3) / 4, 256, 0, stream>>>(nfbf, e_fwd, e_rev, row_in, col_in,
                                               row_out, col_out, compf_u, compr_u);

    k_gemm<<<(NN + 127) / 128, 256, 0, stream>>>((const unsigned short*)compf_u,
                                                 (const unsigned short*)compr_u,
                                                 nfbf, wbf, biasc, outp);

    k_evec<<<1, 256, 0, stream>>>(W_rel, b_rel, e_fwd, e_rev, outp);
}

// Round 4
// 252.800 us; speedup vs baseline: 1.9367x; 1.1834x over previous
//
#include <hip/hip_runtime.h>
#include <stdint.h>

#define NN 100000
#define NE 1000000
#define HID 128
#define NB 391            // ceil(NN/256) buckets of 256 nodes

typedef __attribute__((ext_vector_type(4))) float f32x4;
typedef __attribute__((ext_vector_type(4))) unsigned u32x4;
typedef __attribute__((ext_vector_type(8))) short short8;
typedef __attribute__((ext_vector_type(8))) __bf16 bf16x8;

union V8 { short8 s; bf16x8 b; };

__device__ __forceinline__ unsigned short f2bf(float f) {
    unsigned u = __float_as_uint(f);
    unsigned r = u + 0x7fffu + ((u >> 16) & 1u);
    return (unsigned short)(r >> 16);
}
__device__ __forceinline__ float bf2f(unsigned short h) {
    return __uint_as_float(((unsigned)h) << 16);
}

// ---- cast n_feat f32 -> bf16, 8 elems/thread ----
__global__ void k_cast(const float* __restrict__ in, unsigned* __restrict__ outp) {
    int t = blockIdx.x * blockDim.x + threadIdx.x;
    if (t >= NN * HID / 8) return;
    const f32x4* pin = (const f32x4*)in;
    f32x4 a = pin[2 * t], b = pin[2 * t + 1];
    u32x4 o;
    o[0] = (unsigned)f2bf(a[0]) | ((unsigned)f2bf(a[1]) << 16);
    o[1] = (unsigned)f2bf(a[2]) | ((unsigned)f2bf(a[3]) << 16);
    o[2] = (unsigned)f2bf(b[0]) | ((unsigned)f2bf(b[1]) << 16);
    o[3] = (unsigned)f2bf(b[2]) | ((unsigned)f2bf(b[3]) << 16);
    ((u32x4*)outp)[t] = o;
}

// ---- W_I*(2/3), W_O*(2/3), W_S*(1/3) -> bf16 [3][128][128]; combined bias ----
__global__ void k_prepw(const float* __restrict__ WI, const float* __restrict__ WO,
                        const float* __restrict__ WS, const float* __restrict__ bI,
                        const float* __restrict__ bO, const float* __restrict__ bS,
                        unsigned short* __restrict__ Wbf, float* __restrict__ biasc) {
    int t = blockIdx.x * blockDim.x + threadIdx.x;
    if (t < 3 * HID * HID) {
        int p = t >> 14, i = t & 16383;
        const float* Wsrc = (p == 0) ? WI : ((p == 1) ? WO : WS);
        float scale = (p == 2) ? (1.0f / 3.0f) : (2.0f / 3.0f);
        Wbf[t] = f2bf(Wsrc[i] * scale);
    }
    if (t < HID) biasc[t] = (2.0f / 3.0f) * (bI[t] + bO[t]) + (1.0f / 3.0f) * bS[t];
}

// ---- bucket counting: LDS histograms, one global atomic per (block,bucket) ----
__global__ __launch_bounds__(256) void k_bincount(
        const int* __restrict__ src, const int* __restrict__ dst,
        int* __restrict__ bcntD, int* __restrict__ bcntS) {
    __shared__ int hD[NB], hS[NB];
    int tid = threadIdx.x;
    for (int b = tid; b < NB; b += 256) { hD[b] = 0; hS[b] = 0; }
    __syncthreads();
    int base = blockIdx.x * 8192;
    #pragma unroll
    for (int i = 0; i < 32; ++i) {
        int e = base + i * 256 + tid;
        if (e < NE) {
            atomicAdd(&hD[dst[e] >> 8], 1);
            atomicAdd(&hS[src[e] >> 8], 1);
        }
    }
    __syncthreads();
    for (int b = tid; b < NB; b += 256) {
        if (hD[b]) atomicAdd(&bcntD[b], hD[b]);
        if (hS[b]) atomicAdd(&bcntS[b], hS[b]);
    }
}

// ---- scan bucket counts -> bases + cursors (one block, both dirs) ----
__global__ __launch_bounds__(512) void k_bucketscan(
        const int* __restrict__ bcntD, const int* __restrict__ bcntS,
        int* __restrict__ bbaseD, int* __restrict__ bbaseS,
        int* __restrict__ bcurD, int* __restrict__ bcurS) {
    __shared__ int wtot[8];
    int t = threadIdx.x, lane = t & 63, w = t >> 6;
    #pragma unroll
    for (int dir = 0; dir < 2; ++dir) {
        const int* cnt = dir ? bcntS : bcntD;
        int* bb = dir ? bbaseS : bbaseD;
        int* bc = dir ? bcurS : bcurD;
        int v = (t < NB) ? cnt[t] : 0;
        int x = v;
        #pragma unroll
        for (int off = 1; off < 64; off <<= 1) {
            int y = __shfl_up(x, off);
            if (lane >= off) x += y;
        }
        if (lane == 63) wtot[w] = x;
        __syncthreads();
        int wbase = 0;
        for (int j = 0; j < w; ++j) wbase += wtot[j];
        int incl = wbase + x;
        if (t < NB) { bb[t] = incl - v; bc[t] = incl - v; }
        if (t == NB - 1) bb[NB] = incl;
        __syncthreads();
    }
}

// ---- bin fill: scatter edges into bucket-contiguous packed arrays ----
// packed = (other_node << 8) | (key_node & 255)
__global__ __launch_bounds__(256) void k_binfill(
        const int* __restrict__ src, const int* __restrict__ dst,
        int* __restrict__ bcurD, int* __restrict__ bcurS,
        unsigned* __restrict__ binD, unsigned* __restrict__ binS) {
    __shared__ int hD[NB], hS[NB];
    int tid = threadIdx.x;
    for (int b = tid; b < NB; b += 256) { hD[b] = 0; hS[b] = 0; }
    __syncthreads();
    int base = blockIdx.x * 8192;
    int s[32], d[32];
    #pragma unroll
    for (int i = 0; i < 32; ++i) {
        int e = base + i * 256 + tid;
        s[i] = -1; d[i] = -1;
        if (e < NE) { s[i] = src[e]; d[i] = dst[e]; }
    }
    #pragma unroll
    for (int i = 0; i < 32; ++i) {
        if (s[i] >= 0) {
            atomicAdd(&hD[d[i] >> 8], 1);
            atomicAdd(&hS[s[i] >> 8], 1);
        }
    }
    __syncthreads();
    for (int b = tid; b < NB; b += 256) {
        int c = hD[b];
        hD[b] = c ? atomicAdd(&bcurD[b], c) : 0;
        c = hS[b];
        hS[b] = c ? atomicAdd(&bcurS[b], c) : 0;
    }
    __syncthreads();
    #pragma unroll
    for (int i = 0; i < 32; ++i) {
        if (s[i] >= 0) {
            int p = atomicAdd(&hD[d[i] >> 8], 1);
            binD[p] = ((unsigned)s[i] << 8) | ((unsigned)d[i] & 255u);
            int q = atomicAdd(&hS[s[i] >> 8], 1);
            binS[q] = ((unsigned)d[i] << 8) | ((unsigned)s[i] & 255u);
        }
    }
}

// ---- per-bucket counting sort -> CSR col + row_ptr (one block per bucket+dir) ----
__global__ __launch_bounds__(256) void k_bucketsort(
        const unsigned* __restrict__ binD, const unsigned* __restrict__ binS,
        const int* __restrict__ bbaseD, const int* __restrict__ bbaseS,
        int* __restrict__ row_in, int* __restrict__ row_out,
        int* __restrict__ col_in, int* __restrict__ col_out) {
    __shared__ int c[256];
    __shared__ int wtot[4];
    int bid = blockIdx.x;
    int dir = (bid >= NB) ? 1 : 0;
    int b = dir ? (bid - NB) : bid;
    const unsigned* bin = dir ? binS : binD;
    const int* bb = dir ? bbaseS : bbaseD;
    int* row = dir ? row_out : row_in;
    int* col = dir ? col_out : col_in;

    int tid = threadIdx.x, lane = tid & 63, w = tid >> 6;
    int base = bb[b], cnt = bb[b + 1] - base;
    int node0 = b << 8;
    int M = NN - node0; if (M > 256) M = 256;

    c[tid] = 0;
    __syncthreads();
    for (int k = tid; k < cnt; k += 256)
        atomicAdd(&c[bin[base + k] & 255u], 1);
    __syncthreads();
    int v = c[tid];
    int x = v;
    #pragma unroll
    for (int off = 1; off < 64; off <<= 1) {
        int y = __shfl_up(x, off);
        if (lane >= off) x += y;
    }
    if (lane == 63) wtot[w] = x;
    __syncthreads();
    int wbase = 0;
    for (int j = 0; j < w; ++j) wbase += wtot[j];
    int incl = wbase + x;
    if (tid < M) row[node0 + tid + 1] = base + incl;
    if (b == 0 && tid == 0) row[0] = 0;
    __syncthreads();
    c[tid] = base + incl - v;   // cursor = exclusive
    __syncthreads();
    for (int k = tid; k < cnt; k += 256) {
        unsigned pk = bin[base + k];
        int p = atomicAdd(&c[pk & 255u], 1);
        col[p] = (int)(pk >> 8);
    }
}

// ---- gather: one wave per (node,dir); 4 neighbor-groups x 16B lanes, unroll 4 ----
__global__ __launch_bounds__(256) void k_gather(
        const unsigned short* __restrict__ nf,
        const float* __restrict__ e_fwd, const float* __restrict__ e_rev,
        const int* __restrict__ row_in, const int* __restrict__ col_in,
        const int* __restrict__ row_out, const int* __restrict__ col_out,
        u32x4* __restrict__ comp_f, u32x4* __restrict__ comp_r) {
    int gwid = (int)(((unsigned)blockIdx.x * blockDim.x + threadIdx.x) >> 6);
    if (gwid >= 2 * NN) return;
    int node = gwid >> 1;
    int dir = gwid & 1;
    int lane = threadIdx.x & 63;
    int g = lane >> 4;        // neighbor slot within group-of-4
    int l = lane & 15;        // column block: cols l*8 .. l*8+7

    const int* row = dir ? row_out : row_in;
    const int* col = dir ? col_out : col_in;
    const float* ev = dir ? e_rev : e_fwd;
    u32x4* outp = dir ? comp_r : comp_f;

    int rs = row[node], re = row[node + 1];
    int deg = re - rs;

    float acc[8];
    #pragma unroll
    for (int i = 0; i < 8; ++i) acc[i] = 0.0f;

    for (int k = rs; k < re; k += 16) {
        u32x4 pv[4];
        #pragma unroll
        for (int u = 0; u < 4; ++u) {
            int j = k + 4 * u + g;
            pv[u] = (u32x4){0u, 0u, 0u, 0u};
            if (j < re) {
                int nb = col[j];
                pv[u] = *(const u32x4*)(nf + (((size_t)nb) << 7) + (l << 3));
            }
        }
        #pragma unroll
        for (int u = 0; u < 4; ++u) {
            #pragma unroll
            for (int h = 0; h < 4; ++h) {
                acc[2 * h + 0] += bf2f((unsigned short)(pv[u][h] & 0xffffu));
                acc[2 * h + 1] += bf2f((unsigned short)(pv[u][h] >> 16));
            }
        }
    }

    #pragma unroll
    for (int i = 0; i < 8; ++i) {
        acc[i] += __shfl_xor(acc[i], 16);
        acc[i] += __shfl_xor(acc[i], 32);
    }

    if (g == 0) {
        float degf = (float)deg;
        float rn = (deg > 0) ? (1.0f / sqrtf(degf)) : 1.0f;
        f32x4 e0 = *(const f32x4*)(ev + (l << 3));
        f32x4 e1 = *(const f32x4*)(ev + (l << 3) + 4);
        float evv[8] = {e0[0], e0[1], e0[2], e0[3], e1[0], e1[1], e1[2], e1[3]};
        u32x4 o;
        #pragma unroll
        for (int h = 0; h < 4; ++h) {
            float c0 = (acc[2 * h + 0] - degf * evv[2 * h + 0]) * rn;
            float c1 = (acc[2 * h + 1] - degf * evv[2 * h + 1]) * rn;
            o[h] = (unsigned)f2bf(c0) | ((unsigned)f2bf(c1) << 16);
        }
        // 16 u32x4 (256 B) per node row; lane l owns bytes [l*16, l*16+16)
        outp[(size_t)node * 16 + l] = o;
    }
}

// ---- fused 3-path GEMM: out = comp_f@WI'^T + comp_r@WO'^T + nf@WS'^T + biasc ----
__global__ __launch_bounds__(256) void k_gemm(
        const unsigned short* __restrict__ comp_f, const unsigned short* __restrict__ comp_r,
        const unsigned short* __restrict__ nf, const unsigned short* __restrict__ Wbf,
        const float* __restrict__ biasc, float* __restrict__ outp) {
    int w = threadIdx.x >> 6, lane = threadIdx.x & 63;
    int rowbase = blockIdx.x * 128 + w * 32;
    if (rowbase >= NN) return;
    int lm = lane & 15;
    int lk = (lane >> 4) * 8;

    f32x4 acc[2][8];
    #pragma unroll
    for (int m = 0; m < 2; ++m)
        #pragma unroll
        for (int n = 0; n < 8; ++n) {
            acc[m][n][0] = 0.0f; acc[m][n][1] = 0.0f;
            acc[m][n][2] = 0.0f; acc[m][n][3] = 0.0f;
        }

    #pragma unroll
    for (int p = 0; p < 3; ++p) {
        const unsigned short* A = (p == 0) ? comp_f : ((p == 1) ? comp_r : nf);
        const unsigned short* Wp = Wbf + p * HID * HID;
        #pragma unroll
        for (int kb = 0; kb < 4; ++kb) {
            int k0 = kb * 32 + lk;
            int r0 = rowbase + lm, r1 = r0 + 16;
            V8 a0, a1;
            a0.s = (short8){0,0,0,0,0,0,0,0};
            a1.s = a0.s;
            if (r0 < NN) a0.s = *(const short8*)(A + (size_t)r0 * HID + k0);
            if (r1 < NN) a1.s = *(const short8*)(A + (size_t)r1 * HID + k0);
            #pragma unroll
            for (int n = 0; n < 8; ++n) {
                V8 bb;
                bb.s = *(const short8*)(Wp + (size_t)(n * 16 + lm) * HID + k0);
                acc[0][n] = __builtin_amdgcn_mfma_f32_16x16x32_bf16(a0.b, bb.b, acc[0][n], 0, 0, 0);
                acc[1][n] = __builtin_amdgcn_mfma_f32_16x16x32_bf16(a1.b, bb.b, acc[1][n], 0, 0, 0);
            }
        }
    }
    #pragma unroll
    for (int n = 0; n < 8; ++n) {
        int cc = n * 16 + lm;
        float bias = biasc[cc];
        #pragma unroll
        for (int m = 0; m < 2; ++m) {
            #pragma unroll
            for (int i = 0; i < 4; ++i) {
                int row = rowbase + m * 16 + (lane >> 4) * 4 + i;
                if (row < NN) outp[(size_t)row * HID + cc] = acc[m][n][i] + bias;
            }
        }
    }
}

// ---- edge-feature update: e_out = W_rel @ e + b_rel (exact f32) ----
__global__ void k_evec(const float* __restrict__ W_rel, const float* __restrict__ b_rel,
                       const float* __restrict__ e_fwd, const float* __restrict__ e_rev,
                       float* __restrict__ outp) {
    int t = threadIdx.x;  // 256 threads: 0..127 fwd, 128..255 rev
    int cc = t & 127;
    const float* e = (t < 128) ? e_fwd : e_rev;
    float s = b_rel[cc];
    #pragma unroll 4
    for (int k = 0; k < HID; ++k) s += W_rel[cc * HID + k] * e[k];
    outp[(size_t)NN * HID + ((t < 128) ? 0 : HID) + cc] = s;
}

extern "C" void kernel_launch(void* const* d_in, const int* in_sizes, int n_in,
                              void* d_out, int out_size, void* d_ws, size_t ws_size,
                              hipStream_t stream) {
    const float* n_feat = (const float*)d_in[0];
    const float* e_fwd  = (const float*)d_in[1];
    const float* e_rev  = (const float*)d_in[2];
    const float* W_I    = (const float*)d_in[3];
    const float* b_I    = (const float*)d_in[4];
    const float* W_O    = (const float*)d_in[5];
    const float* b_O    = (const float*)d_in[6];
    const float* W_S    = (const float*)d_in[7];
    const float* b_S    = (const float*)d_in[8];
    const float* W_rel  = (const float*)d_in[9];
    const float* b_rel  = (const float*)d_in[10];
    const int*   src    = (const int*)d_in[11];
    const int*   dst    = (const int*)d_in[12];
    float* outp = (float*)d_out;

    uint8_t* ws = (uint8_t*)d_ws;
    size_t off = 0;
    auto alloc = [&](size_t bytes) -> size_t {
        size_t r = off;
        off = (off + bytes + 255) & ~(size_t)255;
        return r;
    };
    size_t o_nfbf   = alloc((size_t)NN * HID * 2);
    size_t o_compf  = alloc((size_t)NN * HID * 2);
    size_t o_compr  = alloc((size_t)NN * HID * 2);
    size_t o_wbf    = alloc((size_t)3 * HID * HID * 2);
    size_t o_biasc  = alloc(HID * 4);
    size_t o_rowin  = alloc((size_t)(NN + 1) * 4);
    size_t o_rowout = alloc((size_t)(NN + 1) * 4);
    size_t o_colin  = alloc((size_t)NE * 4);
    size_t o_colout = alloc((size_t)NE * 4);
    size_t o_binD   = alloc((size_t)NE * 4);
    size_t o_binS   = alloc((size_t)NE * 4);
    size_t o_bcnt   = alloc((size_t)2 * NB * 4);
    size_t o_bbaseD = alloc((size_t)(NB + 1) * 4);
    size_t o_bbaseS = alloc((size_t)(NB + 1) * 4);
    size_t o_bcurD  = alloc((size_t)NB * 4);
    size_t o_bcurS  = alloc((size_t)NB * 4);
    (void)ws_size; (void)in_sizes; (void)n_in; (void)out_size;

    unsigned short* nfbf  = (unsigned short*)(ws + o_nfbf);
    u32x4*     compf_v    = (u32x4*)(ws + o_compf);
    u32x4*     compr_v    = (u32x4*)(ws + o_compr);
    unsigned short* wbf   = (unsigned short*)(ws + o_wbf);
    float*     biasc      = (float*)(ws + o_biasc);
    int* row_in  = (int*)(ws + o_rowin);
    int* row_out = (int*)(ws + o_rowout);
    int* col_in  = (int*)(ws + o_colin);
    int* col_out = (int*)(ws + o_colout);
    unsigned* binD = (unsigned*)(ws + o_binD);
    unsigned* binS = (unsigned*)(ws + o_binS);
    int* bcntD   = (int*)(ws + o_bcnt);
    int* bcntS   = bcntD + NB;
    int* bbaseD  = (int*)(ws + o_bbaseD);
    int* bbaseS  = (int*)(ws + o_bbaseS);
    int* bcurD   = (int*)(ws + o_bcurD);
    int* bcurS   = (int*)(ws + o_bcurS);

    hipMemsetAsync(ws + o_bcnt, 0, (size_t)2 * NB * 4, stream);

    k_cast<<<(NN * HID / 8 + 255) / 256, 256, 0, stream>>>(n_feat, (unsigned*)nfbf);
    k_prepw<<<(3 * HID * HID + 255) / 256, 256, 0, stream>>>(W_I, W_O, W_S, b_I, b_O, b_S, wbf, biasc);

    const int nbinblk = (NE + 8191) / 8192;  // 123
    k_bincount<<<nbinblk, 256, 0, stream>>>(src, dst, bcntD, bcntS);
    k_bucketscan<<<1, 512, 0, stream>>>(bcntD, bcntS, bbaseD, bbaseS, bcurD, bcurS);
    k_binfill<<<nbinblk, 256, 0, stream>>>(src, dst, bcurD, bcurS, binD, binS);
    k_bucketsort<<<2 * NB, 256, 0, stream>>>(binD, binS, bbaseD, bbaseS,
                                             row_in, row_out, col_in, col_out);

    // one wave per (node, dir): 2*NN waves, 4 waves/block
    k_gather<<<(2 * NN + 3) / 4, 256, 0, stream>>>(nfbf, e_fwd, e_rev, row_in, col_in,
                                                   row_out, col_out, compf_v, compr_v);

    k_gemm<<<(NN + 127) / 128, 256, 0, stream>>>((const unsigned short*)compf_v,
                                                 (const unsigned short*)compr_v,
                                                 nfbf, wbf, biasc, outp);

    k_evec<<<1, 256, 0, stream>>>(W_rel, b_rel, e_fwd, e_rev, outp);
}

// Round 10
// 250.381 us; speedup vs baseline: 1.9554x; 1.0097x over previous
//
#include <hip/hip_runtime.h>
#include <stdint.h>

#define NN 100000
#define NE 1000000
#define HID 128
#define NB 391            // ceil(NN/256) buckets of 256 nodes

typedef __attribute__((ext_vector_type(4))) float f32x4;
typedef __attribute__((ext_vector_type(4))) unsigned u32x4;
typedef __attribute__((ext_vector_type(8))) short short8;
typedef __attribute__((ext_vector_type(8))) __bf16 bf16x8;

union V8 { short8 s; bf16x8 b; };
union AW { unsigned w[4]; bf16x8 b; };
union BP { struct { unsigned long long lo, hi; } u; bf16x8 b; };

__device__ __forceinline__ unsigned short f2bf(float f) {
    unsigned u = __float_as_uint(f);
    unsigned r = u + 0x7fffu + ((u >> 16) & 1u);
    return (unsigned short)(r >> 16);
}
__device__ __forceinline__ float bf2f(unsigned short h) {
    return __uint_as_float(((unsigned)h) << 16);
}

// ---- cast n_feat f32 -> bf16, 8 elems/thread ----
__global__ void k_cast(const float* __restrict__ in, unsigned* __restrict__ outp) {
    int t = blockIdx.x * blockDim.x + threadIdx.x;
    if (t >= NN * HID / 8) return;
    const f32x4* pin = (const f32x4*)in;
    f32x4 a = pin[2 * t], b = pin[2 * t + 1];
    u32x4 o;
    o[0] = (unsigned)f2bf(a[0]) | ((unsigned)f2bf(a[1]) << 16);
    o[1] = (unsigned)f2bf(a[2]) | ((unsigned)f2bf(a[3]) << 16);
    o[2] = (unsigned)f2bf(b[0]) | ((unsigned)f2bf(b[1]) << 16);
    o[3] = (unsigned)f2bf(b[2]) | ((unsigned)f2bf(b[3]) << 16);
    ((u32x4*)outp)[t] = o;
}

// ---- W_I*(2/3), W_O*(2/3), W_S*(1/3) -> bf16 [3][128][128]; combined bias ----
__global__ void k_prepw(const float* __restrict__ WI, const float* __restrict__ WO,
                        const float* __restrict__ WS, const float* __restrict__ bI,
                        const float* __restrict__ bO, const float* __restrict__ bS,
                        unsigned short* __restrict__ Wbf, float* __restrict__ biasc) {
    int t = blockIdx.x * blockDim.x + threadIdx.x;
    if (t < 3 * HID * HID) {
        int p = t >> 14, i = t & 16383;
        const float* Wsrc = (p == 0) ? WI : ((p == 1) ? WO : WS);
        float scale = (p == 2) ? (1.0f / 3.0f) : (2.0f / 3.0f);
        Wbf[t] = f2bf(Wsrc[i] * scale);
    }
    if (t < HID) biasc[t] = (2.0f / 3.0f) * (bI[t] + bO[t]) + (1.0f / 3.0f) * bS[t];
}

// ---- bucket counting: LDS histograms, one global atomic per (block,bucket) ----
__global__ __launch_bounds__(256) void k_bincount(
        const int* __restrict__ src, const int* __restrict__ dst,
        int* __restrict__ bcntD, int* __restrict__ bcntS) {
    __shared__ int hD[NB], hS[NB];
    int tid = threadIdx.x;
    for (int b = tid; b < NB; b += 256) { hD[b] = 0; hS[b] = 0; }
    __syncthreads();
    int base = blockIdx.x * 8192;
    #pragma unroll
    for (int i = 0; i < 32; ++i) {
        int e = base + i * 256 + tid;
        if (e < NE) {
            atomicAdd(&hD[dst[e] >> 8], 1);
            atomicAdd(&hS[src[e] >> 8], 1);
        }
    }
    __syncthreads();
    for (int b = tid; b < NB; b += 256) {
        if (hD[b]) atomicAdd(&bcntD[b], hD[b]);
        if (hS[b]) atomicAdd(&bcntS[b], hS[b]);
    }
}

// ---- scan bucket counts -> bases + cursors (one block, both dirs) ----
__global__ __launch_bounds__(512) void k_bucketscan(
        const int* __restrict__ bcntD, const int* __restrict__ bcntS,
        int* __restrict__ bbaseD, int* __restrict__ bbaseS,
        int* __restrict__ bcurD, int* __restrict__ bcurS) {
    __shared__ int wtot[8];
    int t = threadIdx.x, lane = t & 63, w = t >> 6;
    #pragma unroll
    for (int dir = 0; dir < 2; ++dir) {
        const int* cnt = dir ? bcntS : bcntD;
        int* bb = dir ? bbaseS : bbaseD;
        int* bc = dir ? bcurS : bcurD;
        int v = (t < NB) ? cnt[t] : 0;
        int x = v;
        #pragma unroll
        for (int off = 1; off < 64; off <<= 1) {
            int y = __shfl_up(x, off);
            if (lane >= off) x += y;
        }
        if (lane == 63) wtot[w] = x;
        __syncthreads();
        int wbase = 0;
        for (int j = 0; j < w; ++j) wbase += wtot[j];
        int incl = wbase + x;
        if (t < NB) { bb[t] = incl - v; bc[t] = incl - v; }
        if (t == NB - 1) bb[NB] = incl;
        __syncthreads();
    }
}

// ---- bin fill: scatter edges into bucket-contiguous packed arrays ----
// packed = (other_node << 8) | (key_node & 255)
__global__ __launch_bounds__(256) void k_binfill(
        const int* __restrict__ src, const int* __restrict__ dst,
        int* __restrict__ bcurD, int* __restrict__ bcurS,
        unsigned* __restrict__ binD, unsigned* __restrict__ binS) {
    __shared__ int hD[NB], hS[NB];
    int tid = threadIdx.x;
    for (int b = tid; b < NB; b += 256) { hD[b] = 0; hS[b] = 0; }
    __syncthreads();
    int base = blockIdx.x * 8192;
    int s[32], d[32];
    #pragma unroll
    for (int i = 0; i < 32; ++i) {
        int e = base + i * 256 + tid;
        s[i] = -1; d[i] = -1;
        if (e < NE) { s[i] = src[e]; d[i] = dst[e]; }
    }
    #pragma unroll
    for (int i = 0; i < 32; ++i) {
        if (s[i] >= 0) {
            atomicAdd(&hD[d[i] >> 8], 1);
            atomicAdd(&hS[s[i] >> 8], 1);
        }
    }
    __syncthreads();
    for (int b = tid; b < NB; b += 256) {
        int c = hD[b];
        hD[b] = c ? atomicAdd(&bcurD[b], c) : 0;
        c = hS[b];
        hS[b] = c ? atomicAdd(&bcurS[b], c) : 0;
    }
    __syncthreads();
    #pragma unroll
    for (int i = 0; i < 32; ++i) {
        if (s[i] >= 0) {
            int p = atomicAdd(&hD[d[i] >> 8], 1);
            binD[p] = ((unsigned)s[i] << 8) | ((unsigned)d[i] & 255u);
            int q = atomicAdd(&hS[s[i] >> 8], 1);
            binS[q] = ((unsigned)d[i] << 8) | ((unsigned)s[i] & 255u);
        }
    }
}

// ---- per-bucket counting sort -> CSR col + row_ptr + dest-local-16 labels ----
__global__ __launch_bounds__(256) void k_bucketsort(
        const unsigned* __restrict__ binD, const unsigned* __restrict__ binS,
        const int* __restrict__ bbaseD, const int* __restrict__ bbaseS,
        int* __restrict__ row_in, int* __restrict__ row_out,
        int* __restrict__ col_in, int* __restrict__ col_out,
        unsigned char* __restrict__ dloc_in, unsigned char* __restrict__ dloc_out) {
    __shared__ int c[256];
    __shared__ int wtot[4];
    int bid = blockIdx.x;
    int dir = (bid >= NB) ? 1 : 0;
    int b = dir ? (bid - NB) : bid;
    const unsigned* bin = dir ? binS : binD;
    const int* bb = dir ? bbaseS : bbaseD;
    int* row = dir ? row_out : row_in;
    int* col = dir ? col_out : col_in;
    unsigned char* dlc = dir ? dloc_out : dloc_in;

    int tid = threadIdx.x, lane = tid & 63, w = tid >> 6;
    int base = bb[b], cnt = bb[b + 1] - base;
    int node0 = b << 8;
    int M = NN - node0; if (M > 256) M = 256;

    c[tid] = 0;
    __syncthreads();
    for (int k = tid; k < cnt; k += 256)
        atomicAdd(&c[bin[base + k] & 255u], 1);
    __syncthreads();
    int v = c[tid];
    int x = v;
    #pragma unroll
    for (int off = 1; off < 64; off <<= 1) {
        int y = __shfl_up(x, off);
        if (lane >= off) x += y;
    }
    if (lane == 63) wtot[w] = x;
    __syncthreads();
    int wbase = 0;
    for (int j = 0; j < w; ++j) wbase += wtot[j];
    int incl = wbase + x;
    if (tid < M) row[node0 + tid + 1] = base + incl;
    if (b == 0 && tid == 0) row[0] = 0;
    __syncthreads();
    c[tid] = base + incl - v;   // cursor = exclusive
    __syncthreads();
    for (int k = tid; k < cnt; k += 256) {
        unsigned pk = bin[base + k];
        int p = atomicAdd(&c[pk & 255u], 1);
        col[p] = (int)(pk >> 8);
        dlc[p] = (unsigned char)(pk & 15u);   // dest-local within 16-group
    }
}

typedef __attribute__((address_space(3))) unsigned char as3u8;
typedef __attribute__((address_space(3))) unsigned as3u32;
typedef __attribute__((address_space(1))) const unsigned as1cu32;

// ---- MFMA aggregation: one wave per (16-node group, dir) ----
// LDS layout per wave: [cb=8][k=32][16 cols] bf16 (byte = cb*1024 + k*32 + 2*ci).
// Staged by 8x global_load_lds (call I=cb): lane l -> row kslot=l>>1, half h=l&1,
// LDS dest = base + I*1024 + 16*l (HW: wave-uniform base + lane*16).
// tr-read model (from m156+m162): per-lane byte addr A (plus additive offset:N);
// elem j reads byte (A&~127) + ((A>>3)&15)*2 + 32*j  -- 128B window, col = A[6:3].
// lane l: A = (l>>4)*256 + (l&15)*8, offsets nb*1024 (j=0..3) / +128 (j=4..7)
// -> elem j = X[(l>>4)*8 + j][nb*16 + (l&15)] == MFMA B-frag.
__global__ __launch_bounds__(256) void k_agg(
        const unsigned char* __restrict__ nf,   // (NN+1) rows x 256 B bf16
        const float* __restrict__ e_fwd, const float* __restrict__ e_rev,
        const int* __restrict__ row_in, const int* __restrict__ col_in,
        const unsigned char* __restrict__ dloc_in,
        const int* __restrict__ row_out, const int* __restrict__ col_out,
        const unsigned char* __restrict__ dloc_out,
        unsigned* __restrict__ comp_f, unsigned* __restrict__ comp_r) {
    __shared__ __align__(1024) unsigned char smem[4][8192];
    int warp = threadIdx.x >> 6;
    int l = threadIdx.x & 63;
    int gwid = blockIdx.x * 4 + warp;      // 12500 waves exactly
    int dir = gwid & 1;
    int grp = gwid >> 1;
    int node0 = grp << 4;

    const int* row = dir ? row_out : row_in;
    const int* col = dir ? col_out : col_in;
    const unsigned char* dloc = dir ? dloc_out : dloc_in;
    const float* ev = dir ? e_rev : e_fwd;
    unsigned* outp = dir ? comp_r : comp_f;

    int h = l & 1;
    int kslot = l >> 1;                    // neighbor row this lane stages
    int lm = l & 15;
    int kg = (l >> 4) * 8;                 // B/A fragment k-base for this lane

    // true AS(3) pointers: 32-bit, value == raw LDS byte offset
    as3u8* ldsp = (as3u8*)&smem[warp][0];
    as3u8* trp  = ldsp + ((lm << 3) + ((l >> 4) << 8));   // col in addr bits [6:3]

    int ebase = row[node0];
    int eend  = row[node0 + 16];

    f32x4 acc[8];
    #pragma unroll
    for (int nb = 0; nb < 8; ++nb) {
        acc[nb][0] = 0.0f; acc[nb][1] = 0.0f; acc[nb][2] = 0.0f; acc[nb][3] = 0.0f;
    }

    while (ebase < eend) {
        int e = ebase + (l & 31);
        int rowid = (e < eend) ? col[e] : NN;            // NN = zero row
        int dl    = (e < eend) ? (int)dloc[e] : 255;
        int rowk  = __shfl(rowid, kslot);
        const unsigned char* gp = nf + (((size_t)rowk) << 8) + (h << 4);
#define GLL(I) __builtin_amdgcn_global_load_lds( \
            (as1cu32*)(gp + (I) * 32), \
            (as3u32*)(ldsp + (I) * 1024), 16, 0, 0)
        GLL(0); GLL(1); GLL(2); GLL(3); GLL(4); GLL(5); GLL(6); GLL(7);
#undef GLL

        // A one-hot fragment: a[j] = (dloc[ebase + kg + j] == lm) ? 1.0bf : 0
        AW a;
        #pragma unroll
        for (int j2 = 0; j2 < 4; ++j2) {
            int d0 = __shfl(dl, kg + 2 * j2);
            int d1 = __shfl(dl, kg + 2 * j2 + 1);
            unsigned lo = (d0 == lm) ? 0x3F80u : 0u;
            unsigned hi = (d1 == lm) ? 0x3F80u : 0u;
            a.w[j2] = lo | (hi << 16);
        }

        asm volatile("s_waitcnt vmcnt(0)" ::: "memory");
        __builtin_amdgcn_sched_barrier(0);

        unsigned long long t0[8], t1[8];
        #pragma unroll
        for (int nb = 0; nb < 8; ++nb) {
            asm volatile("ds_read_b64_tr_b16 %0, %1 offset:%2"
                         : "=&v"(t0[nb]) : "v"(trp), "i"(nb * 1024));
            asm volatile("ds_read_b64_tr_b16 %0, %1 offset:%2"
                         : "=&v"(t1[nb]) : "v"(trp), "i"(nb * 1024 + 128));
        }
        asm volatile("s_waitcnt lgkmcnt(0)" ::: "memory");
        __builtin_amdgcn_sched_barrier(0);

        #pragma unroll
        for (int nb = 0; nb < 8; ++nb) {
            BP bp;
            bp.u.lo = t0[nb];
            bp.u.hi = t1[nb];
            acc[nb] = __builtin_amdgcn_mfma_f32_16x16x32_bf16(a.b, bp.b, acc[nb], 0, 0, 0);
        }
        ebase += 32;
    }

    // epilogue: comp[m][c] = (D - deg*ev[c]) * rsqrt(max(deg,1))
    int rp = row[node0 + ((l < 17) ? l : 16)];
    int degi = __shfl(rp, l + 1) - rp;      // valid lanes 0..15
    float degfv = (float)degi;
    float rnv = (degi > 0) ? (1.0f / sqrtf(degfv)) : 1.0f;

    float evv[8];
    #pragma unroll
    for (int nb = 0; nb < 8; ++nb) evv[nb] = ev[nb * 16 + lm];

    #pragma unroll
    for (int i = 0; i < 4; ++i) {
        int m = ((l >> 4) << 2) + i;
        float dm = __shfl(degfv, m);
        float rm = __shfl(rnv, m);
        #pragma unroll
        for (int nb = 0; nb < 8; ++nb) {
            float v = (acc[nb][i] - dm * evv[nb]) * rm;
            float v2 = __shfl_xor(v, 1);
            if ((l & 1) == 0) {
                unsigned dw = (unsigned)f2bf(v) | ((unsigned)f2bf(v2) << 16);
                outp[(size_t)(node0 + m) * 64 + nb * 8 + (lm >> 1)] = dw;
            }
        }
    }
}

// ---- fused 3-path GEMM: out = comp_f@WI'^T + comp_r@WO'^T + nf@WS'^T + biasc ----
__global__ __launch_bounds__(256) void k_gemm(
        const unsigned short* __restrict__ comp_f, const unsigned short* __restrict__ comp_r,
        const unsigned short* __restrict__ nf, const unsigned short* __restrict__ Wbf,
        const float* __restrict__ biasc, float* __restrict__ outp) {
    int w = threadIdx.x >> 6, lane = threadIdx.x & 63;
    int rowbase = blockIdx.x * 128 + w * 32;
    if (rowbase >= NN) return;
    int lm = lane & 15;
    int lk = (lane >> 4) * 8;

    f32x4 acc[2][8];
    #pragma unroll
    for (int m = 0; m < 2; ++m)
        #pragma unroll
        for (int n = 0; n < 8; ++n) {
            acc[m][n][0] = 0.0f; acc[m][n][1] = 0.0f;
            acc[m][n][2] = 0.0f; acc[m][n][3] = 0.0f;
        }

    #pragma unroll
    for (int p = 0; p < 3; ++p) {
        const unsigned short* A = (p == 0) ? comp_f : ((p == 1) ? comp_r : nf);
        const unsigned short* Wp = Wbf + p * HID * HID;
        #pragma unroll
        for (int kb = 0; kb < 4; ++kb) {
            int k0 = kb * 32 + lk;
            int r0 = rowbase + lm, r1 = r0 + 16;
            V8 a0, a1;
            a0.s = (short8){0,0,0,0,0,0,0,0};
            a1.s = a0.s;
            if (r0 < NN) a0.s = *(const short8*)(A + (size_t)r0 * HID + k0);
            if (r1 < NN) a1.s = *(const short8*)(A + (size_t)r1 * HID + k0);
            #pragma unroll
            for (int n = 0; n < 8; ++n) {
                V8 bb;
                bb.s = *(const short8*)(Wp + (size_t)(n * 16 + lm) * HID + k0);
                acc[0][n] = __builtin_amdgcn_mfma_f32_16x16x32_bf16(a0.b, bb.b, acc[0][n], 0, 0, 0);
                acc[1][n] = __builtin_amdgcn_mfma_f32_16x16x32_bf16(a1.b, bb.b, acc[1][n], 0, 0, 0);
            }
        }
    }
    #pragma unroll
    for (int n = 0; n < 8; ++n) {
        int cc = n * 16 + lm;
        float bias = biasc[cc];
        #pragma unroll
        for (int m = 0; m < 2; ++m) {
            #pragma unroll
            for (int i = 0; i < 4; ++i) {
                int row = rowbase + m * 16 + (lane >> 4) * 4 + i;
                if (row < NN) outp[(size_t)row * HID + cc] = acc[m][n][i] + bias;
            }
        }
    }
}

// ---- edge-feature update: e_out = W_rel @ e + b_rel (exact f32) ----
__global__ void k_evec(const float* __restrict__ W_rel, const float* __restrict__ b_rel,
                       const float* __restrict__ e_fwd, const float* __restrict__ e_rev,
                       float* __restrict__ outp) {
    int t = threadIdx.x;  // 256 threads: 0..127 fwd, 128..255 rev
    int cc = t & 127;
    const float* e = (t < 128) ? e_fwd : e_rev;
    float s = b_rel[cc];
    #pragma unroll 4
    for (int k = 0; k < HID; ++k) s += W_rel[cc * HID + k] * e[k];
    outp[(size_t)NN * HID + ((t < 128) ? 0 : HID) + cc] = s;
}

extern "C" void kernel_launch(void* const* d_in, const int* in_sizes, int n_in,
                              void* d_out, int out_size, void* d_ws, size_t ws_size,
                              hipStream_t stream) {
    const float* n_feat = (const float*)d_in[0];
    const float* e_fwd  = (const float*)d_in[1];
    const float* e_rev  = (const float*)d_in[2];
    const float* W_I    = (const float*)d_in[3];
    const float* b_I    = (const float*)d_in[4];
    const float* W_O    = (const float*)d_in[5];
    const float* b_O    = (const float*)d_in[6];
    const float* W_S    = (const float*)d_in[7];
    const float* b_S    = (const float*)d_in[8];
    const float* W_rel  = (const float*)d_in[9];
    const float* b_rel  = (const float*)d_in[10];
    const int*   src    = (const int*)d_in[11];
    const int*   dst    = (const int*)d_in[12];
    float* outp = (float*)d_out;

    uint8_t* ws = (uint8_t*)d_ws;
    size_t off = 0;
    auto alloc = [&](size_t bytes) -> size_t {
        size_t r = off;
        off = (off + bytes + 255) & ~(size_t)255;
        return r;
    };
    size_t o_nfbf   = alloc((size_t)(NN + 1) * HID * 2);   // +1 zero row
    size_t o_compf  = alloc((size_t)NN * HID * 2);
    size_t o_compr  = alloc((size_t)NN * HID * 2);
    size_t o_wbf    = alloc((size_t)3 * HID * HID * 2);
    size_t o_biasc  = alloc(HID * 4);
    size_t o_rowin  = alloc((size_t)(NN + 1) * 4);
    size_t o_rowout = alloc((size_t)(NN + 1) * 4);
    size_t o_colin  = alloc((size_t)NE * 4);
    size_t o_colout = alloc((size_t)NE * 4);
    size_t o_dlin   = alloc((size_t)NE);
    size_t o_dlout  = alloc((size_t)NE);
    size_t o_binD   = alloc((size_t)NE * 4);
    size_t o_binS   = alloc((size_t)NE * 4);
    size_t o_bcnt   = alloc((size_t)2 * NB * 4);
    size_t o_bbaseD = alloc((size_t)(NB + 1) * 4);
    size_t o_bbaseS = alloc((size_t)(NB + 1) * 4);
    size_t o_bcurD  = alloc((size_t)NB * 4);
    size_t o_bcurS  = alloc((size_t)NB * 4);
    (void)ws_size; (void)in_sizes; (void)n_in; (void)out_size;

    unsigned short* nfbf  = (unsigned short*)(ws + o_nfbf);
    unsigned*  compf_u    = (unsigned*)(ws + o_compf);
    unsigned*  compr_u    = (unsigned*)(ws + o_compr);
    unsigned short* wbf   = (unsigned short*)(ws + o_wbf);
    float*     biasc      = (float*)(ws + o_biasc);
    int* row_in  = (int*)(ws + o_rowin);
    int* row_out = (int*)(ws + o_rowout);
    int* col_in  = (int*)(ws + o_colin);
    int* col_out = (int*)(ws + o_colout);
    unsigned char* dloc_in  = (unsigned char*)(ws + o_dlin);
    unsigned char* dloc_out = (unsigned char*)(ws + o_dlout);
    unsigned* binD = (unsigned*)(ws + o_binD);
    unsigned* binS = (unsigned*)(ws + o_binS);
    int* bcntD   = (int*)(ws + o_bcnt);
    int* bcntS   = bcntD + NB;
    int* bbaseD  = (int*)(ws + o_bbaseD);
    int* bbaseS  = (int*)(ws + o_bbaseS);
    int* bcurD   = (int*)(ws + o_bcurD);
    int* bcurS   = (int*)(ws + o_bcurS);

    (void)hipMemsetAsync(ws + o_bcnt, 0, (size_t)2 * NB * 4, stream);
    (void)hipMemsetAsync(ws + o_nfbf + (size_t)NN * HID * 2, 0, HID * 2, stream);  // zero row NN

    k_cast<<<(NN * HID / 8 + 255) / 256, 256, 0, stream>>>(n_feat, (unsigned*)nfbf);
    k_prepw<<<(3 * HID * HID + 255) / 256, 256, 0, stream>>>(W_I, W_O, W_S, b_I, b_O, b_S, wbf, biasc);

    const int nbinblk = (NE + 8191) / 8192;  // 123
    k_bincount<<<nbinblk, 256, 0, stream>>>(src, dst, bcntD, bcntS);
    k_bucketscan<<<1, 512, 0, stream>>>(bcntD, bcntS, bbaseD, bbaseS, bcurD, bcurS);
    k_binfill<<<nbinblk, 256, 0, stream>>>(src, dst, bcurD, bcurS, binD, binS);
    k_bucketsort<<<2 * NB, 256, 0, stream>>>(binD, binS, bbaseD, bbaseS,
                                             row_in, row_out, col_in, col_out,
                                             dloc_in, dloc_out);

    // one wave per (16-node group, dir): 6250*2 = 12500 waves, 4 waves/block
    k_agg<<<12500 / 4, 256, 0, stream>>>((const unsigned char*)nfbf, e_fwd, e_rev,
                                         row_in, col_in, dloc_in,
                                         row_out, col_out, dloc_out,
                                         compf_u, compr_u);

    k_gemm<<<(NN + 127) / 128, 256, 0, stream>>>((const unsigned short*)compf_u,
                                                 (const unsigned short*)compr_u,
                                                 nfbf, wbf, biasc, outp);

    k_evec<<<1, 256, 0, stream>>>(W_rel, b_rel, e_fwd, e_rev, outp);
}

// Round 11
// 205.440 us; speedup vs baseline: 2.3831x; 1.2188x over previous
//
#include <hip/hip_runtime.h>
#include <stdint.h>

#define NN 100000
#define NE 1000000
#define HID 128
#define NB 391            // ceil(NN/256) buckets of 256 nodes

typedef __attribute__((ext_vector_type(4))) float f32x4;
typedef __attribute__((ext_vector_type(4))) unsigned u32x4;
typedef __attribute__((ext_vector_type(8))) short short8;
typedef __attribute__((ext_vector_type(8))) __bf16 bf16x8;

union V8 { short8 s; bf16x8 b; };
union AW { unsigned w[4]; bf16x8 b; };
union BP { struct { unsigned long long lo, hi; } u; short8 s; bf16x8 b; };

__device__ __forceinline__ unsigned short f2bf(float f) {
    unsigned u = __float_as_uint(f);
    unsigned r = u + 0x7fffu + ((u >> 16) & 1u);
    return (unsigned short)(r >> 16);
}

// ---- cast n_feat f32 -> bf16, 8 elems/thread ----
__global__ void k_cast(const float* __restrict__ in, unsigned* __restrict__ outp) {
    int t = blockIdx.x * blockDim.x + threadIdx.x;
    if (t >= NN * HID / 8) return;
    const f32x4* pin = (const f32x4*)in;
    f32x4 a = pin[2 * t], b = pin[2 * t + 1];
    u32x4 o;
    o[0] = (unsigned)f2bf(a[0]) | ((unsigned)f2bf(a[1]) << 16);
    o[1] = (unsigned)f2bf(a[2]) | ((unsigned)f2bf(a[3]) << 16);
    o[2] = (unsigned)f2bf(b[0]) | ((unsigned)f2bf(b[1]) << 16);
    o[3] = (unsigned)f2bf(b[2]) | ((unsigned)f2bf(b[3]) << 16);
    ((u32x4*)outp)[t] = o;
}

// ---- W_I*(2/3), W_O*(2/3), W_S*(1/3) -> bf16 [3][128][128]; combined bias ----
__global__ void k_prepw(const float* __restrict__ WI, const float* __restrict__ WO,
                        const float* __restrict__ WS, const float* __restrict__ bI,
                        const float* __restrict__ bO, const float* __restrict__ bS,
                        unsigned short* __restrict__ Wbf, float* __restrict__ biasc) {
    int t = blockIdx.x * blockDim.x + threadIdx.x;
    if (t < 3 * HID * HID) {
        int p = t >> 14, i = t & 16383;
        const float* Wsrc = (p == 0) ? WI : ((p == 1) ? WO : WS);
        float scale = (p == 2) ? (1.0f / 3.0f) : (2.0f / 3.0f);
        Wbf[t] = f2bf(Wsrc[i] * scale);
    }
    if (t < HID) biasc[t] = (2.0f / 3.0f) * (bI[t] + bO[t]) + (1.0f / 3.0f) * bS[t];
}

// ---- bucket counting: LDS histograms, one global atomic per (block,bucket) ----
__global__ __launch_bounds__(256) void k_bincount(
        const int* __restrict__ src, const int* __restrict__ dst,
        int* __restrict__ bcntD, int* __restrict__ bcntS) {
    __shared__ int hD[NB], hS[NB];
    int tid = threadIdx.x;
    for (int b = tid; b < NB; b += 256) { hD[b] = 0; hS[b] = 0; }
    __syncthreads();
    int base = blockIdx.x * 8192;
    #pragma unroll
    for (int i = 0; i < 32; ++i) {
        int e = base + i * 256 + tid;
        if (e < NE) {
            atomicAdd(&hD[dst[e] >> 8], 1);
            atomicAdd(&hS[src[e] >> 8], 1);
        }
    }
    __syncthreads();
    for (int b = tid; b < NB; b += 256) {
        if (hD[b]) atomicAdd(&bcntD[b], hD[b]);
        if (hS[b]) atomicAdd(&bcntS[b], hS[b]);
    }
}

// ---- scan bucket counts -> bases + cursors (one block, both dirs) ----
__global__ __launch_bounds__(512) void k_bucketscan(
        const int* __restrict__ bcntD, const int* __restrict__ bcntS,
        int* __restrict__ bbaseD, int* __restrict__ bbaseS,
        int* __restrict__ bcurD, int* __restrict__ bcurS) {
    __shared__ int wtot[8];
    int t = threadIdx.x, lane = t & 63, w = t >> 6;
    #pragma unroll
    for (int dir = 0; dir < 2; ++dir) {
        const int* cnt = dir ? bcntS : bcntD;
        int* bb = dir ? bbaseS : bbaseD;
        int* bc = dir ? bcurS : bcurD;
        int v = (t < NB) ? cnt[t] : 0;
        int x = v;
        #pragma unroll
        for (int off = 1; off < 64; off <<= 1) {
            int y = __shfl_up(x, off);
            if (lane >= off) x += y;
        }
        if (lane == 63) wtot[w] = x;
        __syncthreads();
        int wbase = 0;
        for (int j = 0; j < w; ++j) wbase += wtot[j];
        int incl = wbase + x;
        if (t < NB) { bb[t] = incl - v; bc[t] = incl - v; }
        if (t == NB - 1) bb[NB] = incl;
        __syncthreads();
    }
}

// ---- bin fill: scatter edges into bucket-contiguous packed arrays ----
__global__ __launch_bounds__(256) void k_binfill(
        const int* __restrict__ src, const int* __restrict__ dst,
        int* __restrict__ bcurD, int* __restrict__ bcurS,
        unsigned* __restrict__ binD, unsigned* __restrict__ binS) {
    __shared__ int hD[NB], hS[NB];
    int tid = threadIdx.x;
    for (int b = tid; b < NB; b += 256) { hD[b] = 0; hS[b] = 0; }
    __syncthreads();
    int base = blockIdx.x * 8192;
    int s[32], d[32];
    #pragma unroll
    for (int i = 0; i < 32; ++i) {
        int e = base + i * 256 + tid;
        s[i] = -1; d[i] = -1;
        if (e < NE) { s[i] = src[e]; d[i] = dst[e]; }
    }
    #pragma unroll
    for (int i = 0; i < 32; ++i) {
        if (s[i] >= 0) {
            atomicAdd(&hD[d[i] >> 8], 1);
            atomicAdd(&hS[s[i] >> 8], 1);
        }
    }
    __syncthreads();
    for (int b = tid; b < NB; b += 256) {
        int c = hD[b];
        hD[b] = c ? atomicAdd(&bcurD[b], c) : 0;
        c = hS[b];
        hS[b] = c ? atomicAdd(&bcurS[b], c) : 0;
    }
    __syncthreads();
    #pragma unroll
    for (int i = 0; i < 32; ++i) {
        if (s[i] >= 0) {
            int p = atomicAdd(&hD[d[i] >> 8], 1);
            binD[p] = ((unsigned)s[i] << 8) | ((unsigned)d[i] & 255u);
            int q = atomicAdd(&hS[s[i] >> 8], 1);
            binS[q] = ((unsigned)d[i] << 8) | ((unsigned)s[i] & 255u);
        }
    }
}

// ---- per-bucket counting sort -> CSR col + row_ptr + dest-local-16 labels ----
__global__ __launch_bounds__(256) void k_bucketsort(
        const unsigned* __restrict__ binD, const unsigned* __restrict__ binS,
        const int* __restrict__ bbaseD, const int* __restrict__ bbaseS,
        int* __restrict__ row_in, int* __restrict__ row_out,
        int* __restrict__ col_in, int* __restrict__ col_out,
        unsigned char* __restrict__ dloc_in, unsigned char* __restrict__ dloc_out) {
    __shared__ int c[256];
    __shared__ int wtot[4];
    int bid = blockIdx.x;
    int dir = (bid >= NB) ? 1 : 0;
    int b = dir ? (bid - NB) : bid;
    const unsigned* bin = dir ? binS : binD;
    const int* bb = dir ? bbaseS : bbaseD;
    int* row = dir ? row_out : row_in;
    int* col = dir ? col_out : col_in;
    unsigned char* dlc = dir ? dloc_out : dloc_in;

    int tid = threadIdx.x, lane = tid & 63, w = tid >> 6;
    int base = bb[b], cnt = bb[b + 1] - base;
    int node0 = b << 8;
    int M = NN - node0; if (M > 256) M = 256;

    c[tid] = 0;
    __syncthreads();
    for (int k = tid; k < cnt; k += 256)
        atomicAdd(&c[bin[base + k] & 255u], 1);
    __syncthreads();
    int v = c[tid];
    int x = v;
    #pragma unroll
    for (int off = 1; off < 64; off <<= 1) {
        int y = __shfl_up(x, off);
        if (lane >= off) x += y;
    }
    if (lane == 63) wtot[w] = x;
    __syncthreads();
    int wbase = 0;
    for (int j = 0; j < w; ++j) wbase += wtot[j];
    int incl = wbase + x;
    if (tid < M) row[node0 + tid + 1] = base + incl;
    if (b == 0 && tid == 0) row[0] = 0;
    __syncthreads();
    c[tid] = base + incl - v;   // cursor = exclusive
    __syncthreads();
    for (int k = tid; k < cnt; k += 256) {
        unsigned pk = bin[base + k];
        int p = atomicAdd(&c[pk & 255u], 1);
        col[p] = (int)(pk >> 8);
        dlc[p] = (unsigned char)(pk & 15u);
    }
}

typedef __attribute__((address_space(3))) unsigned char as3u8;
typedef __attribute__((address_space(3))) unsigned as3u32;
typedef __attribute__((address_space(1))) const unsigned as1cu32;

// ---- fused aggregation + output GEMM ----
// Block = 4 warps = 2 groups x 2 dirs. Phase 1: MFMA gather (as r10, verified).
// Phase 2: comp^T image [128feat][16node] bf16 into warp's own (now free)
//          staging LDS [0,4KB). Phase 3 (after barrier): out^T = sum_p W'_p
//          x comp_p^T, warp w handles feat-blocks {2w,2w+1} for both groups.
__global__ __launch_bounds__(256) void k_agg(
        const unsigned char* __restrict__ nf,   // (NN+1) rows x 256 B bf16
        const float* __restrict__ e_fwd, const float* __restrict__ e_rev,
        const int* __restrict__ row_in, const int* __restrict__ col_in,
        const unsigned char* __restrict__ dloc_in,
        const int* __restrict__ row_out, const int* __restrict__ col_out,
        const unsigned char* __restrict__ dloc_out,
        const unsigned short* __restrict__ Wbf, const float* __restrict__ biasc,
        float* __restrict__ outp) {
    __shared__ __align__(1024) unsigned char smem[4][8192];
    int warp = threadIdx.x >> 6;
    int l = threadIdx.x & 63;
    int gbase = blockIdx.x * 2;
    int dir = warp & 1;
    int grp = gbase + (warp >> 1);
    int node0 = grp << 4;

    const int* row = dir ? row_out : row_in;
    const int* col = dir ? col_out : col_in;
    const unsigned char* dloc = dir ? dloc_out : dloc_in;
    const float* ev = dir ? e_rev : e_fwd;

    int h = l & 1;
    int kslot = l >> 1;
    int lm = l & 15;
    int q = l >> 4;
    int kg = q * 8;

    as3u8* ldsp = (as3u8*)&smem[warp][0];
    as3u8* trp  = ldsp + ((lm << 3) + (q << 8));

    int ebase = row[node0];
    int eend  = row[node0 + 16];

    f32x4 acc[8];
    #pragma unroll
    for (int nb = 0; nb < 8; ++nb) {
        acc[nb][0] = 0.0f; acc[nb][1] = 0.0f; acc[nb][2] = 0.0f; acc[nb][3] = 0.0f;
    }

    // ---- phase 1: gather (verified r10 structure) ----
    while (ebase < eend) {
        int e = ebase + (l & 31);
        int rowid = (e < eend) ? col[e] : NN;            // NN = zero row
        int dl    = (e < eend) ? (int)dloc[e] : 255;
        int rowk  = __shfl(rowid, kslot);
        const unsigned char* gp = nf + (((size_t)rowk) << 8) + (h << 4);
#define GLL(I) __builtin_amdgcn_global_load_lds( \
            (as1cu32*)(gp + (I) * 32), \
            (as3u32*)(ldsp + (I) * 1024), 16, 0, 0)
        GLL(0); GLL(1); GLL(2); GLL(3); GLL(4); GLL(5); GLL(6); GLL(7);
#undef GLL

        AW a;
        #pragma unroll
        for (int j2 = 0; j2 < 4; ++j2) {
            int d0 = __shfl(dl, kg + 2 * j2);
            int d1 = __shfl(dl, kg + 2 * j2 + 1);
            unsigned lo = (d0 == lm) ? 0x3F80u : 0u;
            unsigned hi = (d1 == lm) ? 0x3F80u : 0u;
            a.w[j2] = lo | (hi << 16);
        }

        asm volatile("s_waitcnt vmcnt(0)" ::: "memory");
        __builtin_amdgcn_sched_barrier(0);

        unsigned long long t0[8], t1[8];
        #pragma unroll
        for (int nb = 0; nb < 8; ++nb) {
            asm volatile("ds_read_b64_tr_b16 %0, %1 offset:%2"
                         : "=&v"(t0[nb]) : "v"(trp), "i"(nb * 1024));
            asm volatile("ds_read_b64_tr_b16 %0, %1 offset:%2"
                         : "=&v"(t1[nb]) : "v"(trp), "i"(nb * 1024 + 128));
        }
        asm volatile("s_waitcnt lgkmcnt(0)" ::: "memory");
        __builtin_amdgcn_sched_barrier(0);

        #pragma unroll
        for (int nb = 0; nb < 8; ++nb) {
            BP bp;
            bp.u.lo = t0[nb];
            bp.u.hi = t1[nb];
            acc[nb] = __builtin_amdgcn_mfma_f32_16x16x32_bf16(a.b, bp.b, acc[nb], 0, 0, 0);
        }
        ebase += 32;
    }

    // ---- phase 2: scaled comp^T image -> LDS [feat*32 + node*2] ----
    int rp = row[node0 + ((l < 17) ? l : 16)];
    int degi = __shfl(rp, l + 1) - rp;      // valid lanes 0..15
    float degfv = (float)degi;
    float rnv = (degi > 0) ? (1.0f / sqrtf(degfv)) : 1.0f;

    float evv[8];
    #pragma unroll
    for (int nb = 0; nb < 8; ++nb) evv[nb] = ev[nb * 16 + lm];

    #pragma unroll
    for (int ip = 0; ip < 2; ++ip) {
        int m0 = q * 4 + 2 * ip;
        float dm0 = __shfl(degfv, m0), rm0 = __shfl(rnv, m0);
        float dm1 = __shfl(degfv, m0 + 1), rm1 = __shfl(rnv, m0 + 1);
        #pragma unroll
        for (int nb = 0; nb < 8; ++nb) {
            float v0 = (acc[nb][2 * ip]     - dm0 * evv[nb]) * rm0;
            float v1 = (acc[nb][2 * ip + 1] - dm1 * evv[nb]) * rm1;
            unsigned dw = (unsigned)f2bf(v0) | ((unsigned)f2bf(v1) << 16);
            *(as3u32*)(ldsp + (nb * 16 + lm) * 32 + q * 8 + ip * 4) = dw;
        }
    }
    __syncthreads();

    // ---- phase 3: out^T = WI'@compf^T + WO'@compr^T + WS'@nf^T ----
    const unsigned short* nfu = (const unsigned short*)nf;
    int obase = warp * 2;                    // feat blocks 2w, 2w+1
    f32x4 D[2][2];
    #pragma unroll
    for (int a2 = 0; a2 < 2; ++a2)
        #pragma unroll
        for (int b2 = 0; b2 < 2; ++b2) {
            D[a2][b2][0] = 0.0f; D[a2][b2][1] = 0.0f;
            D[a2][b2][2] = 0.0f; D[a2][b2][3] = 0.0f;
        }

    #pragma unroll
    for (int p = 0; p < 3; ++p) {
        V8 A[2][4];
        #pragma unroll
        for (int ob2 = 0; ob2 < 2; ++ob2)
            #pragma unroll
            for (int kb = 0; kb < 4; ++kb)
                A[ob2][kb].s = *(const short8*)(Wbf + p * 16384 +
                    ((obase + ob2) * 16 + lm) * 128 + kb * 32 + q * 8);
        #pragma unroll
        for (int gg = 0; gg < 2; ++gg) {
            BP B[4];
            if (p < 2) {
                unsigned long long tb0[4], tb1[4];
                as3u8* ib = (as3u8*)&smem[gg * 2 + p][0] + ((lm << 3) + (q << 8));
                #pragma unroll
                for (int kb = 0; kb < 4; ++kb) {
                    asm volatile("ds_read_b64_tr_b16 %0, %1 offset:%2"
                                 : "=&v"(tb0[kb]) : "v"(ib), "i"(kb * 1024));
                    asm volatile("ds_read_b64_tr_b16 %0, %1 offset:%2"
                                 : "=&v"(tb1[kb]) : "v"(ib), "i"(kb * 1024 + 128));
                }
                asm volatile("s_waitcnt lgkmcnt(0)" ::: "memory");
                __builtin_amdgcn_sched_barrier(0);
                #pragma unroll
                for (int kb = 0; kb < 4; ++kb) { B[kb].u.lo = tb0[kb]; B[kb].u.hi = tb1[kb]; }
            } else {
                int node = (gbase + gg) * 16 + lm;
                #pragma unroll
                for (int kb = 0; kb < 4; ++kb)
                    B[kb].s = *(const short8*)(nfu + (size_t)node * 128 + kb * 32 + q * 8);
            }
            #pragma unroll
            for (int ob2 = 0; ob2 < 2; ++ob2)
                #pragma unroll
                for (int kb = 0; kb < 4; ++kb)
                    D[ob2][gg] = __builtin_amdgcn_mfma_f32_16x16x32_bf16(
                        A[ob2][kb].b, B[kb].b, D[ob2][gg], 0, 0, 0);
        }
    }

    // stores: out[node][o0..o0+3] = D + bias (coalesced 16B f32x4)
    #pragma unroll
    for (int ob2 = 0; ob2 < 2; ++ob2) {
        int o0 = (obase + ob2) * 16 + q * 4;
        f32x4 bias = *(const f32x4*)(biasc + o0);
        #pragma unroll
        for (int gg = 0; gg < 2; ++gg) {
            int node = (gbase + gg) * 16 + lm;
            f32x4 r = D[ob2][gg] + bias;
            *(f32x4*)(outp + (size_t)node * 128 + o0) = r;
        }
    }
}

// ---- edge-feature update: e_out = W_rel @ e + b_rel (exact f32) ----
__global__ void k_evec(const float* __restrict__ W_rel, const float* __restrict__ b_rel,
                       const float* __restrict__ e_fwd, const float* __restrict__ e_rev,
                       float* __restrict__ outp) {
    int t = threadIdx.x;  // 256 threads: 0..127 fwd, 128..255 rev
    int cc = t & 127;
    const float* e = (t < 128) ? e_fwd : e_rev;
    float s = b_rel[cc];
    #pragma unroll 4
    for (int k = 0; k < HID; ++k) s += W_rel[cc * HID + k] * e[k];
    outp[(size_t)NN * HID + ((t < 128) ? 0 : HID) + cc] = s;
}

extern "C" void kernel_launch(void* const* d_in, const int* in_sizes, int n_in,
                              void* d_out, int out_size, void* d_ws, size_t ws_size,
                              hipStream_t stream) {
    const float* n_feat = (const float*)d_in[0];
    const float* e_fwd  = (const float*)d_in[1];
    const float* e_rev  = (const float*)d_in[2];
    const float* W_I    = (const float*)d_in[3];
    const float* b_I    = (const float*)d_in[4];
    const float* W_O    = (const float*)d_in[5];
    const float* b_O    = (const float*)d_in[6];
    const float* W_S    = (const float*)d_in[7];
    const float* b_S    = (const float*)d_in[8];
    const float* W_rel  = (const float*)d_in[9];
    const float* b_rel  = (const float*)d_in[10];
    const int*   src    = (const int*)d_in[11];
    const int*   dst    = (const int*)d_in[12];
    float* outp = (float*)d_out;

    uint8_t* ws = (uint8_t*)d_ws;
    size_t off = 0;
    auto alloc = [&](size_t bytes) -> size_t {
        size_t r = off;
        off = (off + bytes + 255) & ~(size_t)255;
        return r;
    };
    size_t o_nfbf   = alloc((size_t)(NN + 1) * HID * 2);   // +1 zero row
    size_t o_wbf    = alloc((size_t)3 * HID * HID * 2);
    size_t o_biasc  = alloc(HID * 4);
    size_t o_rowin  = alloc((size_t)(NN + 1) * 4);
    size_t o_rowout = alloc((size_t)(NN + 1) * 4);
    size_t o_colin  = alloc((size_t)NE * 4);
    size_t o_colout = alloc((size_t)NE * 4);
    size_t o_dlin   = alloc((size_t)NE);
    size_t o_dlout  = alloc((size_t)NE);
    size_t o_binD   = alloc((size_t)NE * 4);
    size_t o_binS   = alloc((size_t)NE * 4);
    size_t o_bcnt   = alloc((size_t)2 * NB * 4);
    size_t o_bbaseD = alloc((size_t)(NB + 1) * 4);
    size_t o_bbaseS = alloc((size_t)(NB + 1) * 4);
    size_t o_bcurD  = alloc((size_t)NB * 4);
    size_t o_bcurS  = alloc((size_t)NB * 4);
    (void)ws_size; (void)in_sizes; (void)n_in; (void)out_size;

    unsigned short* nfbf  = (unsigned short*)(ws + o_nfbf);
    unsigned short* wbf   = (unsigned short*)(ws + o_wbf);
    float*     biasc      = (float*)(ws + o_biasc);
    int* row_in  = (int*)(ws + o_rowin);
    int* row_out = (int*)(ws + o_rowout);
    int* col_in  = (int*)(ws + o_colin);
    int* col_out = (int*)(ws + o_colout);
    unsigned char* dloc_in  = (unsigned char*)(ws + o_dlin);
    unsigned char* dloc_out = (unsigned char*)(ws + o_dlout);
    unsigned* binD = (unsigned*)(ws + o_binD);
    unsigned* binS = (unsigned*)(ws + o_binS);
    int* bcntD   = (int*)(ws + o_bcnt);
    int* bcntS   = bcntD + NB;
    int* bbaseD  = (int*)(ws + o_bbaseD);
    int* bbaseS  = (int*)(ws + o_bbaseS);
    int* bcurD   = (int*)(ws + o_bcurD);
    int* bcurS   = (int*)(ws + o_bcurS);

    (void)hipMemsetAsync(ws + o_bcnt, 0, (size_t)2 * NB * 4, stream);
    (void)hipMemsetAsync(ws + o_nfbf + (size_t)NN * HID * 2, 0, HID * 2, stream);  // zero row NN

    k_cast<<<(NN * HID / 8 + 255) / 256, 256, 0, stream>>>(n_feat, (unsigned*)nfbf);
    k_prepw<<<(3 * HID * HID + 255) / 256, 256, 0, stream>>>(W_I, W_O, W_S, b_I, b_O, b_S, wbf, biasc);

    const int nbinblk = (NE + 8191) / 8192;  // 123
    k_bincount<<<nbinblk, 256, 0, stream>>>(src, dst, bcntD, bcntS);
    k_bucketscan<<<1, 512, 0, stream>>>(bcntD, bcntS, bbaseD, bbaseS, bcurD, bcurS);
    k_binfill<<<nbinblk, 256, 0, stream>>>(src, dst, bcurD, bcurS, binD, binS);
    k_bucketsort<<<2 * NB, 256, 0, stream>>>(binD, binS, bbaseD, bbaseS,
                                             row_in, row_out, col_in, col_out,
                                             dloc_in, dloc_out);

    // fused agg+GEMM: 2 groups per block, 6250 groups -> 3125 blocks
    k_agg<<<3125, 256, 0, stream>>>((const unsigned char*)nfbf, e_fwd, e_rev,
                                    row_in, col_in, dloc_in,
                                    row_out, col_out, dloc_out,
                                    wbf, biasc, outp);

    k_evec<<<1, 256, 0, stream>>>(W_rel, b_rel, e_fwd, e_rev, outp);
}

// Round 12
// 193.357 us; speedup vs baseline: 2.5321x; 1.0625x over previous
//
#include <hip/hip_runtime.h>
#include <stdint.h>

#define NN 100000
#define NE 1000000
#define HID 128
#define NB 391            // ceil(NN/256) buckets of 256 nodes

typedef __attribute__((ext_vector_type(4))) float f32x4;
typedef __attribute__((ext_vector_type(4))) unsigned u32x4;
typedef __attribute__((ext_vector_type(8))) short short8;
typedef __attribute__((ext_vector_type(8))) __bf16 bf16x8;

union V8 { short8 s; bf16x8 b; };
union AW { unsigned w[4]; bf16x8 b; };
union BP { struct { unsigned long long lo, hi; } u; short8 s; bf16x8 b; };

__device__ __forceinline__ unsigned short f2bf(float f) {
    unsigned u = __float_as_uint(f);
    unsigned r = u + 0x7fffu + ((u >> 16) & 1u);
    return (unsigned short)(r >> 16);
}

// ---- fused prep: cast | prepw | evec | zero-row | bincount, by blockIdx ----
// [0,6250): cast n_feat->bf16.  [6250,6442): W scale+cast, bias combine.
// 6442: evec (exact f32).  6443: zero row NN.  [6444,6567): bucket histogram.
__global__ __launch_bounds__(256) void k_prep(
        const float* __restrict__ n_feat, unsigned* __restrict__ nfbf_u,
        const float* __restrict__ WI, const float* __restrict__ WO,
        const float* __restrict__ WS, const float* __restrict__ bI,
        const float* __restrict__ bO, const float* __restrict__ bS,
        unsigned short* __restrict__ Wbf, float* __restrict__ biasc,
        const float* __restrict__ W_rel, const float* __restrict__ b_rel,
        const float* __restrict__ e_fwd, const float* __restrict__ e_rev,
        const int* __restrict__ src, const int* __restrict__ dst,
        int* __restrict__ bcntD, int* __restrict__ bcntS,
        float* __restrict__ outp) {
    __shared__ int hD[NB], hS[NB];
    int bb = blockIdx.x;
    int tid = threadIdx.x;
    const int NC = NN * HID / 8 / 256;     // 6250 cast blocks

    if (bb < NC) {
        // ---- cast: 8 f32 -> 8 bf16 per thread ----
        int t = bb * 256 + tid;
        const f32x4* pin = (const f32x4*)n_feat;
        f32x4 a = pin[2 * t], b = pin[2 * t + 1];
        u32x4 o;
        o[0] = (unsigned)f2bf(a[0]) | ((unsigned)f2bf(a[1]) << 16);
        o[1] = (unsigned)f2bf(a[2]) | ((unsigned)f2bf(a[3]) << 16);
        o[2] = (unsigned)f2bf(b[0]) | ((unsigned)f2bf(b[1]) << 16);
        o[3] = (unsigned)f2bf(b[2]) | ((unsigned)f2bf(b[3]) << 16);
        ((u32x4*)nfbf_u)[t] = o;
    } else if (bb < NC + 192) {
        // ---- prepw ----
        int t = (bb - NC) * 256 + tid;
        int p = t >> 14, i = t & 16383;
        const float* Wsrc = (p == 0) ? WI : ((p == 1) ? WO : WS);
        float scale = (p == 2) ? (1.0f / 3.0f) : (2.0f / 3.0f);
        Wbf[t] = f2bf(Wsrc[i] * scale);
        if (t < HID) biasc[t] = (2.0f / 3.0f) * (bI[t] + bO[t]) + (1.0f / 3.0f) * bS[t];
    } else if (bb == NC + 192) {
        // ---- evec: e_out = W_rel @ e + b_rel (exact f32) ----
        int cc = tid & 127;
        const float* e = (tid < 128) ? e_fwd : e_rev;
        float s = b_rel[cc];
        #pragma unroll 4
        for (int k = 0; k < HID; ++k) s += W_rel[cc * HID + k] * e[k];
        outp[(size_t)NN * HID + ((tid < 128) ? 0 : HID) + cc] = s;
    } else if (bb == NC + 193) {
        // ---- zero row NN of nf table ----
        if (tid < 64) nfbf_u[(size_t)NN * 64 + tid] = 0;
    } else {
        // ---- bincount block (bb - NC - 194) of 123 ----
        for (int b = tid; b < NB; b += 256) { hD[b] = 0; hS[b] = 0; }
        __syncthreads();
        int base = (bb - NC - 194) * 8192;
        #pragma unroll
        for (int i = 0; i < 32; ++i) {
            int e = base + i * 256 + tid;
            if (e < NE) {
                atomicAdd(&hD[dst[e] >> 8], 1);
                atomicAdd(&hS[src[e] >> 8], 1);
            }
        }
        __syncthreads();
        for (int b = tid; b < NB; b += 256) {
            if (hD[b]) atomicAdd(&bcntD[b], hD[b]);
            if (hS[b]) atomicAdd(&bcntS[b], hS[b]);
        }
    }
}

// ---- scan bucket counts -> bases + cursors (one block, both dirs) ----
__global__ __launch_bounds__(512) void k_bucketscan(
        const int* __restrict__ bcntD, const int* __restrict__ bcntS,
        int* __restrict__ bbaseD, int* __restrict__ bbaseS,
        int* __restrict__ bcurD, int* __restrict__ bcurS) {
    __shared__ int wtot[8];
    int t = threadIdx.x, lane = t & 63, w = t >> 6;
    #pragma unroll
    for (int dir = 0; dir < 2; ++dir) {
        const int* cnt = dir ? bcntS : bcntD;
        int* bb = dir ? bbaseS : bbaseD;
        int* bc = dir ? bcurS : bcurD;
        int v = (t < NB) ? cnt[t] : 0;
        int x = v;
        #pragma unroll
        for (int off = 1; off < 64; off <<= 1) {
            int y = __shfl_up(x, off);
            if (lane >= off) x += y;
        }
        if (lane == 63) wtot[w] = x;
        __syncthreads();
        int wbase = 0;
        for (int j = 0; j < w; ++j) wbase += wtot[j];
        int incl = wbase + x;
        if (t < NB) { bb[t] = incl - v; bc[t] = incl - v; }
        if (t == NB - 1) bb[NB] = incl;
        __syncthreads();
    }
}

// ---- bin fill: scatter edges into bucket-contiguous packed arrays ----
__global__ __launch_bounds__(256) void k_binfill(
        const int* __restrict__ src, const int* __restrict__ dst,
        int* __restrict__ bcurD, int* __restrict__ bcurS,
        unsigned* __restrict__ binD, unsigned* __restrict__ binS) {
    __shared__ int hD[NB], hS[NB];
    int tid = threadIdx.x;
    for (int b = tid; b < NB; b += 256) { hD[b] = 0; hS[b] = 0; }
    __syncthreads();
    int base = blockIdx.x * 8192;
    int s[32], d[32];
    #pragma unroll
    for (int i = 0; i < 32; ++i) {
        int e = base + i * 256 + tid;
        s[i] = -1; d[i] = -1;
        if (e < NE) { s[i] = src[e]; d[i] = dst[e]; }
    }
    #pragma unroll
    for (int i = 0; i < 32; ++i) {
        if (s[i] >= 0) {
            atomicAdd(&hD[d[i] >> 8], 1);
            atomicAdd(&hS[s[i] >> 8], 1);
        }
    }
    __syncthreads();
    for (int b = tid; b < NB; b += 256) {
        int c = hD[b];
        hD[b] = c ? atomicAdd(&bcurD[b], c) : 0;
        c = hS[b];
        hS[b] = c ? atomicAdd(&bcurS[b], c) : 0;
    }
    __syncthreads();
    #pragma unroll
    for (int i = 0; i < 32; ++i) {
        if (s[i] >= 0) {
            int p = atomicAdd(&hD[d[i] >> 8], 1);
            binD[p] = ((unsigned)s[i] << 8) | ((unsigned)d[i] & 255u);
            int q = atomicAdd(&hS[s[i] >> 8], 1);
            binS[q] = ((unsigned)d[i] << 8) | ((unsigned)s[i] & 255u);
        }
    }
}

// ---- per-bucket counting sort -> CSR col + row_ptr + dest-local-16 labels ----
__global__ __launch_bounds__(256) void k_bucketsort(
        const unsigned* __restrict__ binD, const unsigned* __restrict__ binS,
        const int* __restrict__ bbaseD, const int* __restrict__ bbaseS,
        int* __restrict__ row_in, int* __restrict__ row_out,
        int* __restrict__ col_in, int* __restrict__ col_out,
        unsigned char* __restrict__ dloc_in, unsigned char* __restrict__ dloc_out) {
    __shared__ int c[256];
    __shared__ int wtot[4];
    int bid = blockIdx.x;
    int dir = (bid >= NB) ? 1 : 0;
    int b = dir ? (bid - NB) : bid;
    const unsigned* bin = dir ? binS : binD;
    const int* bb = dir ? bbaseS : bbaseD;
    int* row = dir ? row_out : row_in;
    int* col = dir ? col_out : col_in;
    unsigned char* dlc = dir ? dloc_out : dloc_in;

    int tid = threadIdx.x, lane = tid & 63, w = tid >> 6;
    int base = bb[b], cnt = bb[b + 1] - base;
    int node0 = b << 8;
    int M = NN - node0; if (M > 256) M = 256;

    c[tid] = 0;
    __syncthreads();
    for (int k = tid; k < cnt; k += 256)
        atomicAdd(&c[bin[base + k] & 255u], 1);
    __syncthreads();
    int v = c[tid];
    int x = v;
    #pragma unroll
    for (int off = 1; off < 64; off <<= 1) {
        int y = __shfl_up(x, off);
        if (lane >= off) x += y;
    }
    if (lane == 63) wtot[w] = x;
    __syncthreads();
    int wbase = 0;
    for (int j = 0; j < w; ++j) wbase += wtot[j];
    int incl = wbase + x;
    if (tid < M) row[node0 + tid + 1] = base + incl;
    if (b == 0 && tid == 0) row[0] = 0;
    __syncthreads();
    c[tid] = base + incl - v;   // cursor = exclusive
    __syncthreads();
    for (int k = tid; k < cnt; k += 256) {
        unsigned pk = bin[base + k];
        int p = atomicAdd(&c[pk & 255u], 1);
        col[p] = (int)(pk >> 8);
        dlc[p] = (unsigned char)(pk & 15u);
    }
}

typedef __attribute__((address_space(3))) unsigned char as3u8;
typedef __attribute__((address_space(3))) unsigned as3u32;
typedef __attribute__((address_space(1))) const unsigned as1cu32;

// ---- fused aggregation + output GEMM (verified r11 structure) ----
__global__ __launch_bounds__(256) void k_agg(
        const unsigned char* __restrict__ nf,   // (NN+1) rows x 256 B bf16
        const float* __restrict__ e_fwd, const float* __restrict__ e_rev,
        const int* __restrict__ row_in, const int* __restrict__ col_in,
        const unsigned char* __restrict__ dloc_in,
        const int* __restrict__ row_out, const int* __restrict__ col_out,
        const unsigned char* __restrict__ dloc_out,
        const unsigned short* __restrict__ Wbf, const float* __restrict__ biasc,
        float* __restrict__ outp) {
    __shared__ __align__(1024) unsigned char smem[4][8192];
    int warp = threadIdx.x >> 6;
    int l = threadIdx.x & 63;
    int gbase = blockIdx.x * 2;
    int dir = warp & 1;
    int grp = gbase + (warp >> 1);
    int node0 = grp << 4;

    const int* row = dir ? row_out : row_in;
    const int* col = dir ? col_out : col_in;
    const unsigned char* dloc = dir ? dloc_out : dloc_in;
    const float* ev = dir ? e_rev : e_fwd;

    int h = l & 1;
    int kslot = l >> 1;
    int lm = l & 15;
    int q = l >> 4;
    int kg = q * 8;

    as3u8* ldsp = (as3u8*)&smem[warp][0];
    as3u8* trp  = ldsp + ((lm << 3) + (q << 8));

    int ebase = row[node0];
    int eend  = row[node0 + 16];

    f32x4 acc[8];
    #pragma unroll
    for (int nb = 0; nb < 8; ++nb) {
        acc[nb][0] = 0.0f; acc[nb][1] = 0.0f; acc[nb][2] = 0.0f; acc[nb][3] = 0.0f;
    }

    // ---- phase 1: gather ----
    while (ebase < eend) {
        int e = ebase + (l & 31);
        int rowid = (e < eend) ? col[e] : NN;            // NN = zero row
        int dl    = (e < eend) ? (int)dloc[e] : 255;
        int rowk  = __shfl(rowid, kslot);
        const unsigned char* gp = nf + (((size_t)rowk) << 8) + (h << 4);
#define GLL(I) __builtin_amdgcn_global_load_lds( \
            (as1cu32*)(gp + (I) * 32), \
            (as3u32*)(ldsp + (I) * 1024), 16, 0, 0)
        GLL(0); GLL(1); GLL(2); GLL(3); GLL(4); GLL(5); GLL(6); GLL(7);
#undef GLL

        AW a;
        #pragma unroll
        for (int j2 = 0; j2 < 4; ++j2) {
            int d0 = __shfl(dl, kg + 2 * j2);
            int d1 = __shfl(dl, kg + 2 * j2 + 1);
            unsigned lo = (d0 == lm) ? 0x3F80u : 0u;
            unsigned hi = (d1 == lm) ? 0x3F80u : 0u;
            a.w[j2] = lo | (hi << 16);
        }

        asm volatile("s_waitcnt vmcnt(0)" ::: "memory");
        __builtin_amdgcn_sched_barrier(0);

        unsigned long long t0[8], t1[8];
        #pragma unroll
        for (int nb = 0; nb < 8; ++nb) {
            asm volatile("ds_read_b64_tr_b16 %0, %1 offset:%2"
                         : "=&v"(t0[nb]) : "v"(trp), "i"(nb * 1024));
            asm volatile("ds_read_b64_tr_b16 %0, %1 offset:%2"
                         : "=&v"(t1[nb]) : "v"(trp), "i"(nb * 1024 + 128));
        }
        asm volatile("s_waitcnt lgkmcnt(0)" ::: "memory");
        __builtin_amdgcn_sched_barrier(0);

        #pragma unroll
        for (int nb = 0; nb < 8; ++nb) {
            BP bp;
            bp.u.lo = t0[nb];
            bp.u.hi = t1[nb];
            acc[nb] = __builtin_amdgcn_mfma_f32_16x16x32_bf16(a.b, bp.b, acc[nb], 0, 0, 0);
        }
        ebase += 32;
    }

    // ---- phase 2: scaled comp^T image -> LDS [feat*32 + node*2] ----
    int rp = row[node0 + ((l < 17) ? l : 16)];
    int degi = __shfl(rp, l + 1) - rp;      // valid lanes 0..15
    float degfv = (float)degi;
    float rnv = (degi > 0) ? (1.0f / sqrtf(degfv)) : 1.0f;

    float evv[8];
    #pragma unroll
    for (int nb = 0; nb < 8; ++nb) evv[nb] = ev[nb * 16 + lm];

    #pragma unroll
    for (int ip = 0; ip < 2; ++ip) {
        int m0 = q * 4 + 2 * ip;
        float dm0 = __shfl(degfv, m0), rm0 = __shfl(rnv, m0);
        float dm1 = __shfl(degfv, m0 + 1), rm1 = __shfl(rnv, m0 + 1);
        #pragma unroll
        for (int nb = 0; nb < 8; ++nb) {
            float v0 = (acc[nb][2 * ip]     - dm0 * evv[nb]) * rm0;
            float v1 = (acc[nb][2 * ip + 1] - dm1 * evv[nb]) * rm1;
            unsigned dw = (unsigned)f2bf(v0) | ((unsigned)f2bf(v1) << 16);
            *(as3u32*)(ldsp + (nb * 16 + lm) * 32 + q * 8 + ip * 4) = dw;
        }
    }
    __syncthreads();

    // ---- phase 3: out^T = WI'@compf^T + WO'@compr^T + WS'@nf^T ----
    const unsigned short* nfu = (const unsigned short*)nf;
    int obase = warp * 2;                    // feat blocks 2w, 2w+1
    f32x4 D[2][2];
    #pragma unroll
    for (int a2 = 0; a2 < 2; ++a2)
        #pragma unroll
        for (int b2 = 0; b2 < 2; ++b2) {
            D[a2][b2][0] = 0.0f; D[a2][b2][1] = 0.0f;
            D[a2][b2][2] = 0.0f; D[a2][b2][3] = 0.0f;
        }

    #pragma unroll
    for (int p = 0; p < 3; ++p) {
        V8 A[2][4];
        #pragma unroll
        for (int ob2 = 0; ob2 < 2; ++ob2)
            #pragma unroll
            for (int kb = 0; kb < 4; ++kb)
                A[ob2][kb].s = *(const short8*)(Wbf + p * 16384 +
                    ((obase + ob2) * 16 + lm) * 128 + kb * 32 + q * 8);
        #pragma unroll
        for (int gg = 0; gg < 2; ++gg) {
            BP B[4];
            if (p < 2) {
                unsigned long long tb0[4], tb1[4];
                as3u8* ib = (as3u8*)&smem[gg * 2 + p][0] + ((lm << 3) + (q << 8));
                #pragma unroll
                for (int kb = 0; kb < 4; ++kb) {
                    asm volatile("ds_read_b64_tr_b16 %0, %1 offset:%2"
                                 : "=&v"(tb0[kb]) : "v"(ib), "i"(kb * 1024));
                    asm volatile("ds_read_b64_tr_b16 %0, %1 offset:%2"
                                 : "=&v"(tb1[kb]) : "v"(ib), "i"(kb * 1024 + 128));
                }
                asm volatile("s_waitcnt lgkmcnt(0)" ::: "memory");
                __builtin_amdgcn_sched_barrier(0);
                #pragma unroll
                for (int kb = 0; kb < 4; ++kb) { B[kb].u.lo = tb0[kb]; B[kb].u.hi = tb1[kb]; }
            } else {
                int node = (gbase + gg) * 16 + lm;
                #pragma unroll
                for (int kb = 0; kb < 4; ++kb)
                    B[kb].s = *(const short8*)(nfu + (size_t)node * 128 + kb * 32 + q * 8);
            }
            #pragma unroll
            for (int ob2 = 0; ob2 < 2; ++ob2)
                #pragma unroll
                for (int kb = 0; kb < 4; ++kb)
                    D[ob2][gg] = __builtin_amdgcn_mfma_f32_16x16x32_bf16(
                        A[ob2][kb].b, B[kb].b, D[ob2][gg], 0, 0, 0);
        }
    }

    // stores: out[node][o0..o0+3] = D + bias (coalesced 16B f32x4)
    #pragma unroll
    for (int ob2 = 0; ob2 < 2; ++ob2) {
        int o0 = (obase + ob2) * 16 + q * 4;
        f32x4 bias = *(const f32x4*)(biasc + o0);
        #pragma unroll
        for (int gg = 0; gg < 2; ++gg) {
            int node = (gbase + gg) * 16 + lm;
            f32x4 r = D[ob2][gg] + bias;
            *(f32x4*)(outp + (size_t)node * 128 + o0) = r;
        }
    }
}

extern "C" void kernel_launch(void* const* d_in, const int* in_sizes, int n_in,
                              void* d_out, int out_size, void* d_ws, size_t ws_size,
                              hipStream_t stream) {
    const float* n_feat = (const float*)d_in[0];
    const float* e_fwd  = (const float*)d_in[1];
    const float* e_rev  = (const float*)d_in[2];
    const float* W_I    = (const float*)d_in[3];
    const float* b_I    = (const float*)d_in[4];
    const float* W_O    = (const float*)d_in[5];
    const float* b_O    = (const float*)d_in[6];
    const float* W_S    = (const float*)d_in[7];
    const float* b_S    = (const float*)d_in[8];
    const float* W_rel  = (const float*)d_in[9];
    const float* b_rel  = (const float*)d_in[10];
    const int*   src    = (const int*)d_in[11];
    const int*   dst    = (const int*)d_in[12];
    float* outp = (float*)d_out;

    uint8_t* ws = (uint8_t*)d_ws;
    size_t off = 0;
    auto alloc = [&](size_t bytes) -> size_t {
        size_t r = off;
        off = (off + bytes + 255) & ~(size_t)255;
        return r;
    };
    size_t o_nfbf   = alloc((size_t)(NN + 1) * HID * 2);   // +1 zero row
    size_t o_wbf    = alloc((size_t)3 * HID * HID * 2);
    size_t o_biasc  = alloc(HID * 4);
    size_t o_rowin  = alloc((size_t)(NN + 1) * 4);
    size_t o_rowout = alloc((size_t)(NN + 1) * 4);
    size_t o_colin  = alloc((size_t)NE * 4);
    size_t o_colout = alloc((size_t)NE * 4);
    size_t o_dlin   = alloc((size_t)NE);
    size_t o_dlout  = alloc((size_t)NE);
    size_t o_binD   = alloc((size_t)NE * 4);
    size_t o_binS   = alloc((size_t)NE * 4);
    size_t o_bcnt   = alloc((size_t)2 * NB * 4);
    size_t o_bbaseD = alloc((size_t)(NB + 1) * 4);
    size_t o_bbaseS = alloc((size_t)(NB + 1) * 4);
    size_t o_bcurD  = alloc((size_t)NB * 4);
    size_t o_bcurS  = alloc((size_t)NB * 4);
    (void)ws_size; (void)in_sizes; (void)n_in; (void)out_size;

    unsigned short* nfbf  = (unsigned short*)(ws + o_nfbf);
    unsigned short* wbf   = (unsigned short*)(ws + o_wbf);
    float*     biasc      = (float*)(ws + o_biasc);
    int* row_in  = (int*)(ws + o_rowin);
    int* row_out = (int*)(ws + o_rowout);
    int* col_in  = (int*)(ws + o_colin);
    int* col_out = (int*)(ws + o_colout);
    unsigned char* dloc_in  = (unsigned char*)(ws + o_dlin);
    unsigned char* dloc_out = (unsigned char*)(ws + o_dlout);
    unsigned* binD = (unsigned*)(ws + o_binD);
    unsigned* binS = (unsigned*)(ws + o_binS);
    int* bcntD   = (int*)(ws + o_bcnt);
    int* bcntS   = bcntD + NB;
    int* bbaseD  = (int*)(ws + o_bbaseD);
    int* bbaseS  = (int*)(ws + o_bbaseS);
    int* bcurD   = (int*)(ws + o_bcurD);
    int* bcurS   = (int*)(ws + o_bcurS);

    (void)hipMemsetAsync(ws + o_bcnt, 0, (size_t)2 * NB * 4, stream);

    // fused prep: 6250 cast + 192 prepw + 1 evec + 1 zero-row + 123 bincount
    k_prep<<<6567, 256, 0, stream>>>(n_feat, (unsigned*)nfbf,
                                     W_I, W_O, W_S, b_I, b_O, b_S, wbf, biasc,
                                     W_rel, b_rel, e_fwd, e_rev,
                                     src, dst, bcntD, bcntS, outp);

    k_bucketscan<<<1, 512, 0, stream>>>(bcntD, bcntS, bbaseD, bbaseS, bcurD, bcurS);
    k_binfill<<<(NE + 8191) / 8192, 256, 0, stream>>>(src, dst, bcurD, bcurS, binD, binS);
    k_bucketsort<<<2 * NB, 256, 0, stream>>>(binD, binS, bbaseD, bbaseS,
                                             row_in, row_out, col_in, col_out,
                                             dloc_in, dloc_out);

    // fused agg+GEMM: 2 groups per block, 6250 groups -> 3125 blocks
    k_agg<<<3125, 256, 0, stream>>>((const unsigned char*)nfbf, e_fwd, e_rev,
                                    row_in, col_in, dloc_in,
                                    row_out, col_out, dloc_out,
                                    wbf, biasc, outp);
}

// Round 13
// 189.416 us; speedup vs baseline: 2.5847x; 1.0208x over previous
//
#include <hip/hip_runtime.h>
#include <stdint.h>

#define NN 100000
#define NE 1000000
#define HID 128
#define NB 391            // ceil(NN/256) buckets of 256 nodes

typedef __attribute__((ext_vector_type(4))) float f32x4;
typedef __attribute__((ext_vector_type(4))) unsigned u32x4;
typedef __attribute__((ext_vector_type(8))) short short8;
typedef __attribute__((ext_vector_type(8))) __bf16 bf16x8;

union V8 { short8 s; bf16x8 b; };
union AW { unsigned w[4]; bf16x8 b; };
union BP { struct { unsigned long long lo, hi; } u; short8 s; bf16x8 b; };

__device__ __forceinline__ unsigned short f2bf(float f) {
    unsigned u = __float_as_uint(f);
    unsigned r = u + 0x7fffu + ((u >> 16) & 1u);
    return (unsigned short)(r >> 16);
}

// ---- fused prep: cast | prepw | evec | zero-row | bincount, by blockIdx ----
__global__ __launch_bounds__(256) void k_prep(
        const float* __restrict__ n_feat, unsigned* __restrict__ nfbf_u,
        const float* __restrict__ WI, const float* __restrict__ WO,
        const float* __restrict__ WS, const float* __restrict__ bI,
        const float* __restrict__ bO, const float* __restrict__ bS,
        unsigned short* __restrict__ Wbf, float* __restrict__ biasc,
        const float* __restrict__ W_rel, const float* __restrict__ b_rel,
        const float* __restrict__ e_fwd, const float* __restrict__ e_rev,
        const int* __restrict__ src, const int* __restrict__ dst,
        int* __restrict__ bcntD, int* __restrict__ bcntS,
        float* __restrict__ outp) {
    __shared__ int hD[NB], hS[NB];
    int bb = blockIdx.x;
    int tid = threadIdx.x;
    const int NC = NN * HID / 8 / 256;     // 6250 cast blocks

    if (bb < NC) {
        int t = bb * 256 + tid;
        const f32x4* pin = (const f32x4*)n_feat;
        f32x4 a = pin[2 * t], b = pin[2 * t + 1];
        u32x4 o;
        o[0] = (unsigned)f2bf(a[0]) | ((unsigned)f2bf(a[1]) << 16);
        o[1] = (unsigned)f2bf(a[2]) | ((unsigned)f2bf(a[3]) << 16);
        o[2] = (unsigned)f2bf(b[0]) | ((unsigned)f2bf(b[1]) << 16);
        o[3] = (unsigned)f2bf(b[2]) | ((unsigned)f2bf(b[3]) << 16);
        ((u32x4*)nfbf_u)[t] = o;
    } else if (bb < NC + 192) {
        int t = (bb - NC) * 256 + tid;
        int p = t >> 14, i = t & 16383;
        const float* Wsrc = (p == 0) ? WI : ((p == 1) ? WO : WS);
        float scale = (p == 2) ? (1.0f / 3.0f) : (2.0f / 3.0f);
        Wbf[t] = f2bf(Wsrc[i] * scale);
        if (t < HID) biasc[t] = (2.0f / 3.0f) * (bI[t] + bO[t]) + (1.0f / 3.0f) * bS[t];
    } else if (bb == NC + 192) {
        int cc = tid & 127;
        const float* e = (tid < 128) ? e_fwd : e_rev;
        float s = b_rel[cc];
        #pragma unroll 4
        for (int k = 0; k < HID; ++k) s += W_rel[cc * HID + k] * e[k];
        outp[(size_t)NN * HID + ((tid < 128) ? 0 : HID) + cc] = s;
    } else if (bb == NC + 193) {
        if (tid < 64) nfbf_u[(size_t)NN * 64 + tid] = 0;
    } else {
        for (int b = tid; b < NB; b += 256) { hD[b] = 0; hS[b] = 0; }
        __syncthreads();
        int base = (bb - NC - 194) * 8192;
        #pragma unroll
        for (int i = 0; i < 32; ++i) {
            int e = base + i * 256 + tid;
            if (e < NE) {
                atomicAdd(&hD[dst[e] >> 8], 1);
                atomicAdd(&hS[src[e] >> 8], 1);
            }
        }
        __syncthreads();
        for (int b = tid; b < NB; b += 256) {
            if (hD[b]) atomicAdd(&bcntD[b], hD[b]);
            if (hS[b]) atomicAdd(&bcntS[b], hS[b]);
        }
    }
}

// ---- scan bucket counts -> bases + cursors (one block, both dirs) ----
__global__ __launch_bounds__(512) void k_bucketscan(
        const int* __restrict__ bcntD, const int* __restrict__ bcntS,
        int* __restrict__ bbaseD, int* __restrict__ bbaseS,
        int* __restrict__ bcurD, int* __restrict__ bcurS) {
    __shared__ int wtot[8];
    int t = threadIdx.x, lane = t & 63, w = t >> 6;
    #pragma unroll
    for (int dir = 0; dir < 2; ++dir) {
        const int* cnt = dir ? bcntS : bcntD;
        int* bb = dir ? bbaseS : bbaseD;
        int* bc = dir ? bcurS : bcurD;
        int v = (t < NB) ? cnt[t] : 0;
        int x = v;
        #pragma unroll
        for (int off = 1; off < 64; off <<= 1) {
            int y = __shfl_up(x, off);
            if (lane >= off) x += y;
        }
        if (lane == 63) wtot[w] = x;
        __syncthreads();
        int wbase = 0;
        for (int j = 0; j < w; ++j) wbase += wtot[j];
        int incl = wbase + x;
        if (t < NB) { bb[t] = incl - v; bc[t] = incl - v; }
        if (t == NB - 1) bb[NB] = incl;
        __syncthreads();
    }
}

// ---- bin fill: scatter edges into bucket-contiguous packed arrays ----
__global__ __launch_bounds__(256) void k_binfill(
        const int* __restrict__ src, const int* __restrict__ dst,
        int* __restrict__ bcurD, int* __restrict__ bcurS,
        unsigned* __restrict__ binD, unsigned* __restrict__ binS) {
    __shared__ int hD[NB], hS[NB];
    int tid = threadIdx.x;
    for (int b = tid; b < NB; b += 256) { hD[b] = 0; hS[b] = 0; }
    __syncthreads();
    int base = blockIdx.x * 8192;
    int s[32], d[32];
    #pragma unroll
    for (int i = 0; i < 32; ++i) {
        int e = base + i * 256 + tid;
        s[i] = -1; d[i] = -1;
        if (e < NE) { s[i] = src[e]; d[i] = dst[e]; }
    }
    #pragma unroll
    for (int i = 0; i < 32; ++i) {
        if (s[i] >= 0) {
            atomicAdd(&hD[d[i] >> 8], 1);
            atomicAdd(&hS[s[i] >> 8], 1);
        }
    }
    __syncthreads();
    for (int b = tid; b < NB; b += 256) {
        int c = hD[b];
        hD[b] = c ? atomicAdd(&bcurD[b], c) : 0;
        c = hS[b];
        hS[b] = c ? atomicAdd(&bcurS[b], c) : 0;
    }
    __syncthreads();
    #pragma unroll
    for (int i = 0; i < 32; ++i) {
        if (s[i] >= 0) {
            int p = atomicAdd(&hD[d[i] >> 8], 1);
            binD[p] = ((unsigned)s[i] << 8) | ((unsigned)d[i] & 255u);
            int q = atomicAdd(&hS[s[i] >> 8], 1);
            binS[q] = ((unsigned)d[i] << 8) | ((unsigned)s[i] & 255u);
        }
    }
}

// ---- per-bucket counting sort -> packed col2 = (other<<4)|dloc + row_ptr ----
__global__ __launch_bounds__(256) void k_bucketsort(
        const unsigned* __restrict__ binD, const unsigned* __restrict__ binS,
        const int* __restrict__ bbaseD, const int* __restrict__ bbaseS,
        int* __restrict__ row_in, int* __restrict__ row_out,
        unsigned* __restrict__ col2_in, unsigned* __restrict__ col2_out) {
    __shared__ int c[256];
    __shared__ int wtot[4];
    int bid = blockIdx.x;
    int dir = (bid >= NB) ? 1 : 0;
    int b = dir ? (bid - NB) : bid;
    const unsigned* bin = dir ? binS : binD;
    const int* bb = dir ? bbaseS : bbaseD;
    int* row = dir ? row_out : row_in;
    unsigned* col2 = dir ? col2_out : col2_in;

    int tid = threadIdx.x, lane = tid & 63, w = tid >> 6;
    int base = bb[b], cnt = bb[b + 1] - base;
    int node0 = b << 8;
    int M = NN - node0; if (M > 256) M = 256;

    c[tid] = 0;
    __syncthreads();
    for (int k = tid; k < cnt; k += 256)
        atomicAdd(&c[bin[base + k] & 255u], 1);
    __syncthreads();
    int v = c[tid];
    int x = v;
    #pragma unroll
    for (int off = 1; off < 64; off <<= 1) {
        int y = __shfl_up(x, off);
        if (lane >= off) x += y;
    }
    if (lane == 63) wtot[w] = x;
    __syncthreads();
    int wbase = 0;
    for (int j = 0; j < w; ++j) wbase += wtot[j];
    int incl = wbase + x;
    if (tid < M) row[node0 + tid + 1] = base + incl;
    if (b == 0 && tid == 0) row[0] = 0;
    __syncthreads();
    c[tid] = base + incl - v;   // cursor = exclusive
    __syncthreads();
    for (int k = tid; k < cnt; k += 256) {
        unsigned pk = bin[base + k];
        int p = atomicAdd(&c[pk & 255u], 1);
        col2[p] = ((pk >> 8) << 4) | (pk & 15u);
    }
}

typedef __attribute__((address_space(3))) unsigned char as3u8;
typedef __attribute__((address_space(3))) unsigned as3u32;
typedef __attribute__((address_space(1))) const unsigned as1cu32;

// ---- fused aggregation + output GEMM, 16-edge chunks / 4KB staging ----
// Staging layout [cb=8][k=16][16cols] bf16 (512B/cb, 4KB): call I covers
// cb {2I, 2I+(l>>5)}: lane l -> row (l&31)>>1, half l&1, src gp0 + I*64,
// dst ldsp + I*1024 (+16l by HW).
// tr-read: trp = (q&1)*256 + lm*8, offs nb*512 / +128 -> B[8(q&1)+j][lm].
// Lanes q>=2 (k=16..31 of the K=32 MFMA): A one-hot forced 0 -> B garbage
// (finite staged bf16) contributes exactly 0.
__global__ __launch_bounds__(256) void k_agg(
        const unsigned char* __restrict__ nf,   // (NN+1) rows x 256 B bf16
        const float* __restrict__ e_fwd, const float* __restrict__ e_rev,
        const int* __restrict__ row_in, const unsigned* __restrict__ col2_in,
        const int* __restrict__ row_out, const unsigned* __restrict__ col2_out,
        const unsigned short* __restrict__ Wbf, const float* __restrict__ biasc,
        float* __restrict__ outp) {
    __shared__ __align__(1024) unsigned char smem[4][4096];
    int warp = threadIdx.x >> 6;
    int l = threadIdx.x & 63;
    int gbase = blockIdx.x * 2;
    int dir = warp & 1;
    int grp = gbase + (warp >> 1);
    int node0 = grp << 4;

    const int* row = dir ? row_out : row_in;
    const unsigned* col2 = dir ? col2_out : col2_in;
    const float* ev = dir ? e_rev : e_fwd;

    int lm = l & 15;
    int q = l >> 4;
    int kg = q * 8;
    int la = l & 15;
    int kslot = (l & 31) >> 1;

    as3u8* ldsp = (as3u8*)&smem[warp][0];
    as3u8* trp  = ldsp + (((q & 1) << 8) + (lm << 3));

    int ecur = row[node0];
    int eend = row[node0 + 16];

    f32x4 acc[8];
    #pragma unroll
    for (int nb = 0; nb < 8; ++nb) {
        acc[nb][0] = 0.0f; acc[nb][1] = 0.0f; acc[nb][2] = 0.0f; acc[nb][3] = 0.0f;
    }

    // ---- phase 1: gather, 16-edge chunks, col2 prefetched one chunk ahead --
    unsigned pk = (ecur + la < eend) ? col2[ecur + la] : ((unsigned)NN << 4);
    while (ecur < eend) {
        int enext = ecur + 16;
        int rowk = __shfl((int)(pk >> 4), kslot);
        const unsigned char* gp = nf + (((size_t)rowk) << 8) +
                                  ((l >> 5) << 5) + ((l & 1) << 4);
#define GLL(I) __builtin_amdgcn_global_load_lds( \
            (as1cu32*)(gp + (I) * 64), \
            (as3u32*)(ldsp + (I) * 1024), 16, 0, 0)
        GLL(0); GLL(1); GLL(2); GLL(3);
#undef GLL
        // prefetch next chunk's packed edges (hides under the drain)
        unsigned pknext = (enext < eend)
            ? ((enext + la < eend) ? col2[enext + la] : ((unsigned)NN << 4))
            : 0u;

        // A one-hot: lanes q>=2 (k 16..31) contribute zero
        int dl = (int)(pk & 15u);
        AW a;
        #pragma unroll
        for (int j2 = 0; j2 < 4; ++j2) {
            int d0 = __shfl(dl, kg + 2 * j2);
            int d1 = __shfl(dl, kg + 2 * j2 + 1);
            unsigned lo = (q < 2 && d0 == lm) ? 0x3F80u : 0u;
            unsigned hi = (q < 2 && d1 == lm) ? 0x3F80u : 0u;
            a.w[j2] = lo | (hi << 16);
        }

        asm volatile("s_waitcnt vmcnt(0)" ::: "memory");
        __builtin_amdgcn_sched_barrier(0);

        unsigned long long t0[8], t1[8];
        #pragma unroll
        for (int nb = 0; nb < 8; ++nb) {
            asm volatile("ds_read_b64_tr_b16 %0, %1 offset:%2"
                         : "=&v"(t0[nb]) : "v"(trp), "i"(nb * 512));
            asm volatile("ds_read_b64_tr_b16 %0, %1 offset:%2"
                         : "=&v"(t1[nb]) : "v"(trp), "i"(nb * 512 + 128));
        }
        asm volatile("s_waitcnt lgkmcnt(0)" ::: "memory");
        __builtin_amdgcn_sched_barrier(0);

        #pragma unroll
        for (int nb = 0; nb < 8; ++nb) {
            BP bp;
            bp.u.lo = t0[nb];
            bp.u.hi = t1[nb];
            acc[nb] = __builtin_amdgcn_mfma_f32_16x16x32_bf16(a.b, bp.b, acc[nb], 0, 0, 0);
        }
        pk = pknext;
        ecur = enext;
    }

    // ---- phase 2: scaled comp^T image -> LDS [feat*32 + node*2] (4KB) ----
    int rp = row[node0 + ((l < 17) ? l : 16)];
    int degi = __shfl(rp, l + 1) - rp;      // valid lanes 0..15
    float degfv = (float)degi;
    float rnv = (degi > 0) ? (1.0f / sqrtf(degfv)) : 1.0f;

    float evv[8];
    #pragma unroll
    for (int nb = 0; nb < 8; ++nb) evv[nb] = ev[nb * 16 + lm];

    #pragma unroll
    for (int ip = 0; ip < 2; ++ip) {
        int m0 = q * 4 + 2 * ip;
        float dm0 = __shfl(degfv, m0), rm0 = __shfl(rnv, m0);
        float dm1 = __shfl(degfv, m0 + 1), rm1 = __shfl(rnv, m0 + 1);
        #pragma unroll
        for (int nb = 0; nb < 8; ++nb) {
            float v0 = (acc[nb][2 * ip]     - dm0 * evv[nb]) * rm0;
            float v1 = (acc[nb][2 * ip + 1] - dm1 * evv[nb]) * rm1;
            unsigned dw = (unsigned)f2bf(v0) | ((unsigned)f2bf(v1) << 16);
            *(as3u32*)(ldsp + (nb * 16 + lm) * 32 + q * 8 + ip * 4) = dw;
        }
    }
    __syncthreads();

    // ---- phase 3: out^T = WI'@compf^T + WO'@compr^T + WS'@nf^T ----
    const unsigned short* nfu = (const unsigned short*)nf;
    int obase = warp * 2;                    // feat blocks 2w, 2w+1
    f32x4 D[2][2];
    #pragma unroll
    for (int a2 = 0; a2 < 2; ++a2)
        #pragma unroll
        for (int b2 = 0; b2 < 2; ++b2) {
            D[a2][b2][0] = 0.0f; D[a2][b2][1] = 0.0f;
            D[a2][b2][2] = 0.0f; D[a2][b2][3] = 0.0f;
        }

    #pragma unroll
    for (int p = 0; p < 3; ++p) {
        V8 A[2][4];
        #pragma unroll
        for (int ob2 = 0; ob2 < 2; ++ob2)
            #pragma unroll
            for (int kb = 0; kb < 4; ++kb)
                A[ob2][kb].s = *(const short8*)(Wbf + p * 16384 +
                    ((obase + ob2) * 16 + lm) * 128 + kb * 32 + q * 8);
        #pragma unroll
        for (int gg = 0; gg < 2; ++gg) {
            BP B[4];
            if (p < 2) {
                unsigned long long tb0[4], tb1[4];
                as3u8* ib = (as3u8*)&smem[gg * 2 + p][0] + ((lm << 3) + (q << 8));
                #pragma unroll
                for (int kb = 0; kb < 4; ++kb) {
                    asm volatile("ds_read_b64_tr_b16 %0, %1 offset:%2"
                                 : "=&v"(tb0[kb]) : "v"(ib), "i"(kb * 1024));
                    asm volatile("ds_read_b64_tr_b16 %0, %1 offset:%2"
                                 : "=&v"(tb1[kb]) : "v"(ib), "i"(kb * 1024 + 128));
                }
                asm volatile("s_waitcnt lgkmcnt(0)" ::: "memory");
                __builtin_amdgcn_sched_barrier(0);
                #pragma unroll
                for (int kb = 0; kb < 4; ++kb) { B[kb].u.lo = tb0[kb]; B[kb].u.hi = tb1[kb]; }
            } else {
                int node = (gbase + gg) * 16 + lm;
                #pragma unroll
                for (int kb = 0; kb < 4; ++kb)
                    B[kb].s = *(const short8*)(nfu + (size_t)node * 128 + kb * 32 + q * 8);
            }
            #pragma unroll
            for (int ob2 = 0; ob2 < 2; ++ob2)
                #pragma unroll
                for (int kb = 0; kb < 4; ++kb)
                    D[ob2][gg] = __builtin_amdgcn_mfma_f32_16x16x32_bf16(
                        A[ob2][kb].b, B[kb].b, D[ob2][gg], 0, 0, 0);
        }
    }

    // stores: out[node][o0..o0+3] = D + bias (coalesced 16B f32x4)
    #pragma unroll
    for (int ob2 = 0; ob2 < 2; ++ob2) {
        int o0 = (obase + ob2) * 16 + q * 4;
        f32x4 bias = *(const f32x4*)(biasc + o0);
        #pragma unroll
        for (int gg = 0; gg < 2; ++gg) {
            int node = (gbase + gg) * 16 + lm;
            f32x4 r = D[ob2][gg] + bias;
            *(f32x4*)(outp + (size_t)node * 128 + o0) = r;
        }
    }
}

extern "C" void kernel_launch(void* const* d_in, const int* in_sizes, int n_in,
                              void* d_out, int out_size, void* d_ws, size_t ws_size,
                              hipStream_t stream) {
    const float* n_feat = (const float*)d_in[0];
    const float* e_fwd  = (const float*)d_in[1];
    const float* e_rev  = (const float*)d_in[2];
    const float* W_I    = (const float*)d_in[3];
    const float* b_I    = (const float*)d_in[4];
    const float* W_O    = (const float*)d_in[5];
    const float* b_O    = (const float*)d_in[6];
    const float* W_S    = (const float*)d_in[7];
    const float* b_S    = (const float*)d_in[8];
    const float* W_rel  = (const float*)d_in[9];
    const float* b_rel  = (const float*)d_in[10];
    const int*   src    = (const int*)d_in[11];
    const int*   dst    = (const int*)d_in[12];
    float* outp = (float*)d_out;

    uint8_t* ws = (uint8_t*)d_ws;
    size_t off = 0;
    auto alloc = [&](size_t bytes) -> size_t {
        size_t r = off;
        off = (off + bytes + 255) & ~(size_t)255;
        return r;
    };
    size_t o_nfbf   = alloc((size_t)(NN + 1) * HID * 2);   // +1 zero row
    size_t o_wbf    = alloc((size_t)3 * HID * HID * 2);
    size_t o_biasc  = alloc(HID * 4);
    size_t o_rowin  = alloc((size_t)(NN + 1) * 4);
    size_t o_rowout = alloc((size_t)(NN + 1) * 4);
    size_t o_col2in = alloc((size_t)NE * 4);
    size_t o_col2out= alloc((size_t)NE * 4);
    size_t o_binD   = alloc((size_t)NE * 4);
    size_t o_binS   = alloc((size_t)NE * 4);
    size_t o_bcnt   = alloc((size_t)2 * NB * 4);
    size_t o_bbaseD = alloc((size_t)(NB + 1) * 4);
    size_t o_bbaseS = alloc((size_t)(NB + 1) * 4);
    size_t o_bcurD  = alloc((size_t)NB * 4);
    size_t o_bcurS  = alloc((size_t)NB * 4);
    (void)ws_size; (void)in_sizes; (void)n_in; (void)out_size;

    unsigned short* nfbf  = (unsigned short*)(ws + o_nfbf);
    unsigned short* wbf   = (unsigned short*)(ws + o_wbf);
    float*     biasc      = (float*)(ws + o_biasc);
    int* row_in  = (int*)(ws + o_rowin);
    int* row_out = (int*)(ws + o_rowout);
    unsigned* col2_in  = (unsigned*)(ws + o_col2in);
    unsigned* col2_out = (unsigned*)(ws + o_col2out);
    unsigned* binD = (unsigned*)(ws + o_binD);
    unsigned* binS = (unsigned*)(ws + o_binS);
    int* bcntD   = (int*)(ws + o_bcnt);
    int* bcntS   = bcntD + NB;
    int* bbaseD  = (int*)(ws + o_bbaseD);
    int* bbaseS  = (int*)(ws + o_bbaseS);
    int* bcurD   = (int*)(ws + o_bcurD);
    int* bcurS   = (int*)(ws + o_bcurS);

    (void)hipMemsetAsync(ws + o_bcnt, 0, (size_t)2 * NB * 4, stream);

    // fused prep: 6250 cast + 192 prepw + 1 evec + 1 zero-row + 123 bincount
    k_prep<<<6567, 256, 0, stream>>>(n_feat, (unsigned*)nfbf,
                                     W_I, W_O, W_S, b_I, b_O, b_S, wbf, biasc,
                                     W_rel, b_rel, e_fwd, e_rev,
                                     src, dst, bcntD, bcntS, outp);

    k_bucketscan<<<1, 512, 0, stream>>>(bcntD, bcntS, bbaseD, bbaseS, bcurD, bcurS);
    k_binfill<<<(NE + 8191) / 8192, 256, 0, stream>>>(src, dst, bcurD, bcurS, binD, binS);
    k_bucketsort<<<2 * NB, 256, 0, stream>>>(binD, binS, bbaseD, bbaseS,
                                             row_in, row_out, col2_in, col2_out);

    // fused agg+GEMM: 2 groups per block, 6250 groups -> 3125 blocks
    k_agg<<<3125, 256, 0, stream>>>((const unsigned char*)nfbf, e_fwd, e_rev,
                                    row_in, col2_in, row_out, col2_out,
                                    wbf, biasc, outp);
}